// Round 9
// baseline (776.452 us; speedup 1.0000x reference)
//
#include <hip/hip_runtime.h>
#include <hip/hip_bf16.h>

// ---------------------------------------------------------------------------
// Treensformer block: x += MHSA(LN1(x)); x += BranchMLP(LN2(x))
// B=64, N_NODES=341, E=512, H=8, hd=64, 4*E=2048, N_LEVELS=4
// R1: MFMA flash attention. R5: branch-MLP ancestor dedup.
// R6/R7: 256^2 deep pipeline -> REGRESSED. R8: 128^2 + fused branch +
//     XCD/A-major remap: 785us. R9: BK64 + XOR swizzle: 751 (conflicts->0).
// R10: gemm64 for proj/w2: 722 (residency mechanism: 72 regs -> 6 blk/CU).
// R11: split-K: REGRESSED (conflicts). R12: launch_bounds(256,6): NULL ->
//     grid depth is the cap; narrow-GEMM structure plateau at w2~121us.
// R13: gemm64 for qkv+branch: REGRESSED (752; branch 121 -> 147us: its
//     grid was already 14 blk/CU deep, halving the tile only doubled
//     B-amplification; FETCH 154MB WRITE 145MB @ 26% HBM). REVERTED.
// R14: revert to R12-exact launch graph, then eliminate the Y->combine->
//     hbuf->w2 intermediate: fuse combine INTO w2's A-staging
//     (gemm64_w2). Each A-stage thread computes its 16-elem h-slice
//     on the fly: b1 (4xf32x4) + up to 5 Y segment-pairs (ancestor bases
//     precomputed once per thread) -> add -> ReLU -> bf16 -> same LDS
//     swizzle/MFMA path. Removes combine dispatch (~45us) + hbuf 89MB W
//     + 89MB R. Y re-reads (gn=4) are L2/L3-absorbed (A-major remap).
//     Numerics identical (same bf16 rounding point as combine_kernel).
// ---------------------------------------------------------------------------

typedef __attribute__((ext_vector_type(8))) __bf16 bf16x8;
typedef __attribute__((ext_vector_type(4))) float f32x4;
typedef __attribute__((ext_vector_type(4))) unsigned int u32x4;

#define GF_RELU    1
#define GF_OUTBF16 2

static __device__ __forceinline__ bf16x8 bzero8() {
    u32x4 z = {0u, 0u, 0u, 0u};
    return __builtin_bit_cast(bf16x8, z);
}

// ---------------------------------------------------------------------------
// Weight transpose+convert: out[n*K + k] = bf16(in[k*N + n]); K is pow2.
// ---------------------------------------------------------------------------
__global__ void transpose_bf16_kernel(const float* __restrict__ in,
                                      __hip_bfloat16* __restrict__ out,
                                      int K, int N, int log2K) {
    int idx = blockIdx.x * 256 + threadIdx.x;
    if (idx >= K * N) return;
    int n = idx >> log2K;
    int k = idx & (K - 1);
    out[idx] = __float2bfloat16(in[(size_t)k * N + n]);
}

// ---------------------------------------------------------------------------
// Pack mlp_M (5,5,2048,512) fp32 -> Wcat bf16 grouped by source depth s.
// ---------------------------------------------------------------------------
__global__ void pack_wcat_kernel(const float* __restrict__ M,
                                 __hip_bfloat16* __restrict__ out) {
    int p = blockIdx.y;
    int s, d;
    if (p < 5)       { s = 0; d = p; }
    else if (p < 9)  { s = 1; d = p - 4; }
    else if (p < 12) { s = 2; d = p - 7; }
    else if (p < 14) { s = 3; d = p - 9; }
    else             { s = 4; d = 4; }
    const int base_lut[5] = {0, 5, 9, 12, 14};
    size_t idx = (size_t)blockIdx.x * 256 + threadIdx.x;  // 0 .. 2048*512-1
    const size_t MB = 2048ull * 512;
    out[(size_t)base_lut[s] * MB + (size_t)(d - s) * MB + idx] =
        __float2bfloat16(M[((size_t)d * 5 + s) * MB + idx]);
}

// ---------------------------------------------------------------------------
// LayerNorm over E=512, one block (256 threads) per token; writes bf16.
// ---------------------------------------------------------------------------
__global__ __launch_bounds__(256) void ln_kernel(const float* __restrict__ x,
                                                 const float* __restrict__ g,
                                                 const float* __restrict__ b,
                                                 __hip_bfloat16* __restrict__ out) {
    int tok = blockIdx.x;
    const float* xr = x + (size_t)tok * 512;
    int t = threadIdx.x;
    float v0 = xr[t], v1 = xr[t + 256];
    float s = v0 + v1;
    float s2 = v0 * v0 + v1 * v1;
    #pragma unroll
    for (int o = 32; o > 0; o >>= 1) {
        s  += __shfl_down(s, o);
        s2 += __shfl_down(s2, o);
    }
    __shared__ float ps[4], ps2[4];
    int w = t >> 6, lane = t & 63;
    if (lane == 0) { ps[w] = s; ps2[w] = s2; }
    __syncthreads();
    if (t == 0) {
        float ts = 0.f, ts2 = 0.f;
        #pragma unroll
        for (int i = 0; i < 4; i++) { ts += ps[i]; ts2 += ps2[i]; }
        ps[0] = ts * (1.f / 512.f);
        ps2[0] = ts2 * (1.f / 512.f);
    }
    __syncthreads();
    float m = ps[0];
    float var = ps2[0] - m * m;
    float r = rsqrtf(var + 1e-5f);
    out[(size_t)tok * 512 + t]       = __float2bfloat16((v0 - m) * r * g[t] + b[t]);
    out[(size_t)tok * 512 + t + 256] = __float2bfloat16((v1 - m) * r * g[t + 256] + b[t + 256]);
}

// ---------------------------------------------------------------------------
// MFMA flash attention (unchanged from R2).
// ---------------------------------------------------------------------------
#define ATT_STR 72
__global__ __launch_bounds__(256) void attn_mfma_kernel(const __hip_bfloat16* __restrict__ qkv,
                                                        __hip_bfloat16* __restrict__ ctx) {
    __shared__ __bf16 kt_lds[64 * ATT_STR];
    __shared__ __bf16 vt_lds[64 * ATT_STR];
    __shared__ __bf16 pbuf[4 * 48 * ATT_STR];

    const int bh = blockIdx.x;
    const int half = blockIdx.y;
    const int b = bh >> 3, h = bh & 7;
    const int tid = threadIdx.x;
    const int w = tid >> 6, lane = tid & 63;
    const int q = lane >> 4, l16 = lane & 15;
    const int rowbase = half * 192 + w * 48;
    __bf16* pw = pbuf + w * 48 * ATT_STR;

    bf16x8 qf[3][2];
    #pragma unroll
    for (int mi = 0; mi < 3; mi++) {
        int row = rowbase + mi * 16 + l16;
        #pragma unroll
        for (int ks = 0; ks < 2; ks++) {
            if (row < 341)
                qf[mi][ks] = *(const bf16x8*)(qkv + (size_t)(b * 341 + row) * 1536 +
                                              h * 64 + ks * 32 + q * 8);
            else
                qf[mi][ks] = bzero8();
        }
    }

    f32x4 O[3][4];
    float mrun[3][4], lrun[3][4];
    #pragma unroll
    for (int mi = 0; mi < 3; mi++) {
        #pragma unroll
        for (int ni = 0; ni < 4; ni++) { f32x4 z = {0.f,0.f,0.f,0.f}; O[mi][ni] = z; }
        #pragma unroll
        for (int rr = 0; rr < 4; rr++) { mrun[mi][rr] = -1e30f; lrun[mi][rr] = 0.f; }
    }

    for (int kt6 = 0; kt6 < 6; kt6++) {
        const int kbase = kt6 * 64;
        __syncthreads();
        {
            int key = tid >> 2, kg = tid & 3;
            int gk = kbase + key;
            bf16x8 a0 = bzero8(), a1 = bzero8();
            if (gk < 341) {
                const __hip_bfloat16* src =
                    qkv + (size_t)(b * 341 + gk) * 1536 + 512 + h * 64 + kg * 16;
                a0 = *(const bf16x8*)src;
                a1 = *(const bf16x8*)(src + 8);
            }
            *(bf16x8*)(kt_lds + key * ATT_STR + kg * 16)     = a0;
            *(bf16x8*)(kt_lds + key * ATT_STR + kg * 16 + 8) = a1;
        }
        {
            int key = tid & 63, dg = tid >> 6;
            int gk = kbase + key;
            bf16x8 a0 = bzero8(), a1 = bzero8();
            if (gk < 341) {
                const __hip_bfloat16* src =
                    qkv + (size_t)(b * 341 + gk) * 1536 + 1024 + h * 64 + dg * 16;
                a0 = *(const bf16x8*)src;
                a1 = *(const bf16x8*)(src + 8);
            }
            #pragma unroll
            for (int j = 0; j < 8; j++) {
                vt_lds[(dg * 16 + j) * ATT_STR + key]     = a0[j];
                vt_lds[(dg * 16 + 8 + j) * ATT_STR + key] = a1[j];
            }
        }
        __syncthreads();

        f32x4 S[3][4];
        #pragma unroll
        for (int mi = 0; mi < 3; mi++)
            #pragma unroll
            for (int ni = 0; ni < 4; ni++) { f32x4 z = {0.f,0.f,0.f,0.f}; S[mi][ni] = z; }
        #pragma unroll
        for (int ks = 0; ks < 2; ks++) {
            bf16x8 bf_[4];
            #pragma unroll
            for (int ni = 0; ni < 4; ni++)
                bf_[ni] = *(const bf16x8*)(kt_lds + (ni * 16 + l16) * ATT_STR + ks * 32 + q * 8);
            #pragma unroll
            for (int mi = 0; mi < 3; mi++)
                #pragma unroll
                for (int ni = 0; ni < 4; ni++)
                    S[mi][ni] = __builtin_amdgcn_mfma_f32_16x16x32_bf16(qf[mi][ks], bf_[ni],
                                                                        S[mi][ni], 0, 0, 0);
        }

        float cmask[4];
        #pragma unroll
        for (int ni = 0; ni < 4; ni++)
            cmask[ni] = (kbase + ni * 16 + l16 < 341) ? 0.f : -1e30f;

        #pragma unroll
        for (int mi = 0; mi < 3; mi++) {
            #pragma unroll
            for (int rr = 0; rr < 4; rr++) {
                float rmax = -1e30f;
                #pragma unroll
                for (int ni = 0; ni < 4; ni++)
                    rmax = fmaxf(rmax, fmaf(S[mi][ni][rr], 0.125f, cmask[ni]));
                rmax = fmaxf(rmax, __shfl_xor(rmax, 1));
                rmax = fmaxf(rmax, __shfl_xor(rmax, 2));
                rmax = fmaxf(rmax, __shfl_xor(rmax, 4));
                rmax = fmaxf(rmax, __shfl_xor(rmax, 8));
                float mnew = fmaxf(mrun[mi][rr], rmax);
                float alpha = __expf(mrun[mi][rr] - mnew);
                mrun[mi][rr] = mnew;
                float psum = 0.f;
                #pragma unroll
                for (int ni = 0; ni < 4; ni++) {
                    float p = __expf(fmaf(S[mi][ni][rr], 0.125f, cmask[ni]) - mnew);
                    S[mi][ni][rr] = p;
                    psum += p;
                    O[mi][ni][rr] *= alpha;
                }
                psum += __shfl_xor(psum, 1);
                psum += __shfl_xor(psum, 2);
                psum += __shfl_xor(psum, 4);
                psum += __shfl_xor(psum, 8);
                lrun[mi][rr] = lrun[mi][rr] * alpha + psum;
            }
            #pragma unroll
            for (int ni = 0; ni < 4; ni++)
                #pragma unroll
                for (int rr = 0; rr < 4; rr++)
                    pw[(mi * 16 + q * 4 + rr) * ATT_STR + ni * 16 + l16] =
                        (__bf16)S[mi][ni][rr];
        }
        __syncthreads();

        #pragma unroll
        for (int ks = 0; ks < 2; ks++) {
            bf16x8 pf[3], vf[4];
            #pragma unroll
            for (int mi = 0; mi < 3; mi++)
                pf[mi] = *(const bf16x8*)(pw + (mi * 16 + l16) * ATT_STR + ks * 32 + q * 8);
            #pragma unroll
            for (int ni = 0; ni < 4; ni++)
                vf[ni] = *(const bf16x8*)(vt_lds + (ni * 16 + l16) * ATT_STR + ks * 32 + q * 8);
            #pragma unroll
            for (int mi = 0; mi < 3; mi++)
                #pragma unroll
                for (int ni = 0; ni < 4; ni++)
                    O[mi][ni] = __builtin_amdgcn_mfma_f32_16x16x32_bf16(pf[mi], vf[ni],
                                                                        O[mi][ni], 0, 0, 0);
        }
    }

    #pragma unroll
    for (int mi = 0; mi < 3; mi++) {
        #pragma unroll
        for (int rr = 0; rr < 4; rr++) {
            int row = rowbase + mi * 16 + q * 4 + rr;
            if (row >= 341) continue;
            float inv = 1.f / lrun[mi][rr];
            __hip_bfloat16* op = ctx + (size_t)(b * 341 + row) * 512 + h * 64;
            #pragma unroll
            for (int ni = 0; ni < 4; ni++)
                op[ni * 16 + l16] = __float2bfloat16(O[mi][ni][rr] * inv);
        }
    }
}

// bijective XCD-aware remap (m204): each XCD gets a contiguous chunk of the
// logical (A-major) tile order -> neighboring tiles sharing an A row-panel
// land on the same XCD's L2.
static __device__ __forceinline__ int xcd_remap(int bid, int nwg) {
    const int xcd = bid & 7, o = bid >> 3;
    const int qq = nwg >> 3, rr = nwg & 7;
    return (xcd < rr ? xcd * (qq + 1) : rr * (qq + 1) + (xcd - rr) * qq) + o;
}

// ---------------------------------------------------------------------------
// gemm128 body (128x128xBK64, register staging, both-sides XOR swizzle).
// Used for qkv (N=1536) and the fused branch GEMM (deep grids, 3 blk/CU).
// ---------------------------------------------------------------------------
template <bool GATHER>
static __device__ __forceinline__ void gemm128_body(
    __hip_bfloat16* As, __hip_bfloat16* Bs,
    const __hip_bfloat16* __restrict__ A, const __hip_bfloat16* __restrict__ Bt,
    const float* __restrict__ bias, const float* __restrict__ resid,
    float* __restrict__ Cf, __hip_bfloat16* __restrict__ Cb,
    int Mrows, int N, int K, int flags, int depth, int bm0, int bn0) {
    const int tid = threadIdx.x;
    const int r = tid >> 1;            // staging row 0..127
    const int khalf = tid & 1;         // 0/1 -> 32-element (64B) half of row
    const int gr = bm0 + r;
    const int gn = bn0 + r;
    const int lane = tid & 63;
    const int w = tid >> 6;
    const int wm = (w >> 1) << 6;
    const int wn = (w & 1) << 6;
    const int q = lane >> 4;
    const int l16 = lane & 15;

    int wsl[4];
    #pragma unroll
    for (int j = 0; j < 4; j++)
        wsl[j] = ((((khalf << 2) | j) ^ (r & 7)) << 3);
    const int rs0 = ((q ^ (l16 & 7)) << 3);
    const int rs1 = (((4 + q) ^ (l16 & 7)) << 3);

    size_t abase;
    if (GATHER) {
        const int dsh = depth << 1;
        const int bmask = (1 << dsh) - 1;
        int b = gr >> dsh;
        int i = gr & bmask;
        int node = (0x55555555 & bmask) + i;   // offs[depth] + i
        abase = ((size_t)(b * 341 + node)) << 9;
    } else {
        abase = (size_t)gr * K;
    }

    f32x4 acc[4][4];
    #pragma unroll
    for (int i = 0; i < 4; i++)
        #pragma unroll
        for (int j = 0; j < 4; j++) {
            f32x4 z = {0.f, 0.f, 0.f, 0.f};
            acc[i][j] = z;
        }

    for (int k0 = 0; k0 < K; k0 += 64) {
        bf16x8 va[4], vb[4];
        if (gr < Mrows) {
            const bf16x8* p = (const bf16x8*)(A + abase + k0 + (khalf << 5));
            #pragma unroll
            for (int j = 0; j < 4; j++) va[j] = p[j];
        } else {
            #pragma unroll
            for (int j = 0; j < 4; j++) va[j] = bzero8();
        }
        {
            const bf16x8* p = (const bf16x8*)(Bt + (size_t)gn * K + k0 + (khalf << 5));
            #pragma unroll
            for (int j = 0; j < 4; j++) vb[j] = p[j];
        }
        __syncthreads();  // previous iteration's fragment reads complete
        #pragma unroll
        for (int j = 0; j < 4; j++) {
            *(bf16x8*)(As + r * 64 + wsl[j]) = va[j];
            *(bf16x8*)(Bs + r * 64 + wsl[j]) = vb[j];
        }
        __syncthreads();
        bf16x8 af[4][2], bfr[4][2];
        #pragma unroll
        for (int mi = 0; mi < 4; mi++) {
            const __hip_bfloat16* rp = As + (wm + mi * 16 + l16) * 64;
            af[mi][0] = *(const bf16x8*)(rp + rs0);
            af[mi][1] = *(const bf16x8*)(rp + rs1);
        }
        #pragma unroll
        for (int ni = 0; ni < 4; ni++) {
            const __hip_bfloat16* rp = Bs + (wn + ni * 16 + l16) * 64;
            bfr[ni][0] = *(const bf16x8*)(rp + rs0);
            bfr[ni][1] = *(const bf16x8*)(rp + rs1);
        }
        #pragma unroll
        for (int ks = 0; ks < 2; ks++)
            #pragma unroll
            for (int mi = 0; mi < 4; mi++)
                #pragma unroll
                for (int ni = 0; ni < 4; ni++)
                    acc[mi][ni] = __builtin_amdgcn_mfma_f32_16x16x32_bf16(
                        af[mi][ks], bfr[ni][ks], acc[mi][ni], 0, 0, 0);
    }

    #pragma unroll
    for (int mi = 0; mi < 4; mi++) {
        #pragma unroll
        for (int rr = 0; rr < 4; rr++) {
            int grow = bm0 + wm + mi * 16 + q * 4 + rr;
            if (grow >= Mrows) continue;
            size_t obase = (size_t)grow * N;
            #pragma unroll
            for (int ni = 0; ni < 4; ni++) {
                int col = bn0 + wn + ni * 16 + l16;
                float v = acc[mi][ni][rr];
                if (bias) v += bias[col];
                if (resid) v += resid[obase + col];
                if (flags & GF_RELU) v = fmaxf(v, 0.f);
                if (flags & GF_OUTBF16)
                    Cb[obase + col] = __float2bfloat16(v);
                else
                    Cf[obase + col] = v;
            }
        }
    }
}

__global__ __launch_bounds__(256) void gemm128(
    const __hip_bfloat16* __restrict__ A, const __hip_bfloat16* __restrict__ Bt,
    const float* __restrict__ bias, const float* __restrict__ resid,
    float* __restrict__ Cf, __hip_bfloat16* __restrict__ Cb,
    int Mrows, int N, int K, int flags, int gridN) {
    __shared__ __hip_bfloat16 As[128 * 64];
    __shared__ __hip_bfloat16 Bs[128 * 64];
    const int lin = xcd_remap(blockIdx.x, gridDim.x);
    const int bx = lin / gridN;           // A-major: consecutive lin share A panel
    const int by = lin - bx * gridN;
    gemm128_body<false>(As, Bs, A, Bt, bias, resid, Cf, Cb,
                        Mrows, N, K, flags, 0, bx << 7, by << 7);
}

// ---------------------------------------------------------------------------
// R10 gemm64: 64(M)x128(N)xBK64 for proj (N=512). 256 threads = 4 waves,
// each wave 64x32 (acc[4][2]). Register staging + XOR slot swizzle.
// ---------------------------------------------------------------------------
__global__ __launch_bounds__(256, 6) void gemm64(
    const __hip_bfloat16* __restrict__ A, const __hip_bfloat16* __restrict__ Bt,
    const float* __restrict__ bias, const float* __restrict__ resid,
    float* __restrict__ Cf, __hip_bfloat16* __restrict__ Cb,
    int Mrows, int N, int K, int flags, int gridN) {
    __shared__ __hip_bfloat16 As[64 * 64];
    __shared__ __hip_bfloat16 Bs[128 * 64];
    const int lin = xcd_remap(blockIdx.x, gridDim.x);
    const int bx = lin / gridN;           // A-major
    const int by = lin - bx * gridN;
    const int bm0 = bx << 6, bn0 = by << 7;

    const int tid = threadIdx.x;
    const int ra = tid >> 2, kq = tid & 3;      // A: 4 threads/row, 2 slots
    const int rb = tid >> 1, khalf = tid & 1;   // B: 2 threads/row, 4 slots
    const int lane = tid & 63;
    const int w = tid >> 6;
    const int wn = w << 5;                      // wave col offset 0/32/64/96
    const int q = lane >> 4;
    const int l16 = lane & 15;

    const int gra = bm0 + ra;
    const int gnb = bn0 + rb;

    int wslA[2];
    #pragma unroll
    for (int j = 0; j < 2; j++)
        wslA[j] = ((((kq << 1) | j) ^ (ra & 7)) << 3);
    int wslB[4];
    #pragma unroll
    for (int j = 0; j < 4; j++)
        wslB[j] = ((((khalf << 2) | j) ^ (rb & 7)) << 3);
    const int rs0 = ((q ^ (l16 & 7)) << 3);
    const int rs1 = (((4 + q) ^ (l16 & 7)) << 3);

    const size_t abase = (size_t)gra * K;

    f32x4 acc[4][2];
    #pragma unroll
    for (int i = 0; i < 4; i++)
        #pragma unroll
        for (int j = 0; j < 2; j++) {
            f32x4 z = {0.f, 0.f, 0.f, 0.f};
            acc[i][j] = z;
        }

    for (int k0 = 0; k0 < K; k0 += 64) {
        bf16x8 va[2], vb[4];
        if (gra < Mrows) {
            const bf16x8* p = (const bf16x8*)(A + abase + k0 + (kq << 4));
            #pragma unroll
            for (int j = 0; j < 2; j++) va[j] = p[j];
        } else {
            #pragma unroll
            for (int j = 0; j < 2; j++) va[j] = bzero8();
        }
        {
            const bf16x8* p = (const bf16x8*)(Bt + (size_t)gnb * K + k0 + (khalf << 5));
            #pragma unroll
            for (int j = 0; j < 4; j++) vb[j] = p[j];
        }
        __syncthreads();  // previous iteration's fragment reads complete
        #pragma unroll
        for (int j = 0; j < 2; j++)
            *(bf16x8*)(As + ra * 64 + wslA[j]) = va[j];
        #pragma unroll
        for (int j = 0; j < 4; j++)
            *(bf16x8*)(Bs + rb * 64 + wslB[j]) = vb[j];
        __syncthreads();
        bf16x8 af[4][2], bfr[2][2];
        #pragma unroll
        for (int mi = 0; mi < 4; mi++) {
            const __hip_bfloat16* rp = As + (mi * 16 + l16) * 64;
            af[mi][0] = *(const bf16x8*)(rp + rs0);
            af[mi][1] = *(const bf16x8*)(rp + rs1);
        }
        #pragma unroll
        for (int ni = 0; ni < 2; ni++) {
            const __hip_bfloat16* rp = Bs + (wn + ni * 16 + l16) * 64;
            bfr[ni][0] = *(const bf16x8*)(rp + rs0);
            bfr[ni][1] = *(const bf16x8*)(rp + rs1);
        }
        #pragma unroll
        for (int ks = 0; ks < 2; ks++)
            #pragma unroll
            for (int mi = 0; mi < 4; mi++)
                #pragma unroll
                for (int ni = 0; ni < 2; ni++)
                    acc[mi][ni] = __builtin_amdgcn_mfma_f32_16x16x32_bf16(
                        af[mi][ks], bfr[ni][ks], acc[mi][ni], 0, 0, 0);
    }

    #pragma unroll
    for (int mi = 0; mi < 4; mi++) {
        #pragma unroll
        for (int rr = 0; rr < 4; rr++) {
            int grow = bm0 + mi * 16 + q * 4 + rr;
            if (grow >= Mrows) continue;
            size_t obase = (size_t)grow * N;
            #pragma unroll
            for (int ni = 0; ni < 2; ni++) {
                int col = bn0 + wn + ni * 16 + l16;
                float v = acc[mi][ni][rr];
                if (bias) v += bias[col];
                if (resid) v += resid[obase + col];
                if (flags & GF_RELU) v = fmaxf(v, 0.f);
                if (flags & GF_OUTBF16)
                    Cb[obase + col] = __float2bfloat16(v);
                else
                    Cf[obase + col] = v;
            }
        }
    }
}

// ---------------------------------------------------------------------------
// R14 gemm64_w2: w2 GEMM with combine FUSED into A-staging.
// out[row,:512] += h[row,:2048] @ w2T^T + b2, where h[row, k] =
//   ReLU( sum_{s<=d} Y_s[ancestor_s(row), (d-s)*2048 + k] + b1[node, k] ).
// A-stage thread (4/row, 16 elems): b1 4xf32x4 + up to 5 Y bf16x8-pairs,
// add, ReLU, cvt bf16 -> same LDS/swizzle/MFMA path as gemm64.
// Ancestor bases precomputed once per thread. Grid 1364 (gm=341, gn=4).
// ---------------------------------------------------------------------------
__global__ __launch_bounds__(256, 6) void gemm64_w2(
    const __hip_bfloat16* __restrict__ Y, const float* __restrict__ b1,
    const __hip_bfloat16* __restrict__ Bt, const float* __restrict__ bias,
    float* __restrict__ outio, int gridN) {
    __shared__ __hip_bfloat16 As[64 * 64];
    __shared__ __hip_bfloat16 Bs[128 * 64];
    const size_t yoff[5] = {0, 655360, 2752512, 9043968, 25821184};
    const int Mrows = 21824, N = 512, K = 2048;

    const int lin = xcd_remap(blockIdx.x, gridDim.x);
    const int bx = lin / gridN;           // A-major
    const int by = lin - bx * gridN;
    const int bm0 = bx << 6, bn0 = by << 7;

    const int tid = threadIdx.x;
    const int ra = tid >> 2, kq = tid & 3;      // A: 4 threads/row, 16 elems
    const int rb = tid >> 1, khalf = tid & 1;   // B: 2 threads/row, 4 slots
    const int lane = tid & 63;
    const int w = tid >> 6;
    const int wn = w << 5;
    const int q = lane >> 4;
    const int l16 = lane & 15;

    const int gnb = bn0 + rb;

    int wslA[2];
    #pragma unroll
    for (int j = 0; j < 2; j++)
        wslA[j] = ((((kq << 1) | j) ^ (ra & 7)) << 3);
    int wslB[4];
    #pragma unroll
    for (int j = 0; j < 4; j++)
        wslB[j] = ((((khalf << 2) | j) ^ (rb & 7)) << 3);
    const int rs0 = ((q ^ (l16 & 7)) << 3);
    const int rs1 = (((4 + q) ^ (l16 & 7)) << 3);

    // ---- per-thread combine bases (row fixed across K-loop) ----
    const int grow = bm0 + ra;                  // < 21824 always (341*64 exact)
    const int b = grow / 341;
    const int node = grow - b * 341;
    const int d = (node >= 85) ? 4 : (node >= 21) ? 3 : (node >= 5) ? 2
                 : (node >= 1) ? 1 : 0;
    const int i = node - (0x55555555 & ((1 << (d << 1)) - 1));
    size_t ybase[5];
    #pragma unroll
    for (int s = 0; s < 5; s++) {
        if (s <= d) {
            int ds = d - s;
            int a = i >> (ds << 1);
            int rowY = (b << (s << 1)) + a;
            ybase[s] = yoff[s] + (size_t)rowY * ((5 - s) << 11) + (ds << 11) +
                       (kq << 4);
        } else {
            ybase[s] = 0;
        }
    }
    const float* b1p = b1 + (size_t)node * 2048 + (kq << 4);

    f32x4 acc[4][2];
    #pragma unroll
    for (int ii = 0; ii < 4; ii++)
        #pragma unroll
        for (int j = 0; j < 2; j++) {
            f32x4 z = {0.f, 0.f, 0.f, 0.f};
            acc[ii][j] = z;
        }

    for (int k0 = 0; k0 < K; k0 += 64) {
        // ---- fused combine: compute h[grow, k0+kq*16 .. +16] ----
        float av[16];
        {
            const f32x4* bp = (const f32x4*)(b1p + k0);
            #pragma unroll
            for (int u = 0; u < 4; u++) {
                f32x4 t = bp[u];
                av[u * 4 + 0] = t[0]; av[u * 4 + 1] = t[1];
                av[u * 4 + 2] = t[2]; av[u * 4 + 3] = t[3];
            }
        }
        #pragma unroll
        for (int s = 0; s < 5; s++) {
            if (s <= d) {
                const bf16x8* yp = (const bf16x8*)(Y + ybase[s] + k0);
                bf16x8 y0 = yp[0], y1 = yp[1];
                #pragma unroll
                for (int u = 0; u < 8; u++) {
                    av[u]     += (float)y0[u];
                    av[u + 8] += (float)y1[u];
                }
            }
        }
        bf16x8 va[2];
        #pragma unroll
        for (int u = 0; u < 8; u++) {
            va[0][u] = (__bf16)fmaxf(av[u], 0.f);
            va[1][u] = (__bf16)fmaxf(av[u + 8], 0.f);
        }
        bf16x8 vb[4];
        {
            const bf16x8* p = (const bf16x8*)(Bt + (size_t)gnb * K + k0 + (khalf << 5));
            #pragma unroll
            for (int j = 0; j < 4; j++) vb[j] = p[j];
        }
        __syncthreads();  // previous iteration's fragment reads complete
        #pragma unroll
        for (int j = 0; j < 2; j++)
            *(bf16x8*)(As + ra * 64 + wslA[j]) = va[j];
        #pragma unroll
        for (int j = 0; j < 4; j++)
            *(bf16x8*)(Bs + rb * 64 + wslB[j]) = vb[j];
        __syncthreads();
        bf16x8 af[4][2], bfr[2][2];
        #pragma unroll
        for (int mi = 0; mi < 4; mi++) {
            const __hip_bfloat16* rp = As + (mi * 16 + l16) * 64;
            af[mi][0] = *(const bf16x8*)(rp + rs0);
            af[mi][1] = *(const bf16x8*)(rp + rs1);
        }
        #pragma unroll
        for (int ni = 0; ni < 2; ni++) {
            const __hip_bfloat16* rp = Bs + (wn + ni * 16 + l16) * 64;
            bfr[ni][0] = *(const bf16x8*)(rp + rs0);
            bfr[ni][1] = *(const bf16x8*)(rp + rs1);
        }
        #pragma unroll
        for (int ks = 0; ks < 2; ks++)
            #pragma unroll
            for (int mi = 0; mi < 4; mi++)
                #pragma unroll
                for (int ni = 0; ni < 2; ni++)
                    acc[mi][ni] = __builtin_amdgcn_mfma_f32_16x16x32_bf16(
                        af[mi][ks], bfr[ni][ks], acc[mi][ni], 0, 0, 0);
    }

    #pragma unroll
    for (int mi = 0; mi < 4; mi++) {
        #pragma unroll
        for (int rr = 0; rr < 4; rr++) {
            int growo = bm0 + mi * 16 + q * 4 + rr;
            if (growo >= Mrows) continue;
            size_t obase = (size_t)growo * N;
            #pragma unroll
            for (int ni = 0; ni < 2; ni++) {
                int col = bn0 + wn + ni * 16 + l16;
                float v = acc[mi][ni][rr] + bias[col] + outio[obase + col];
                outio[obase + col] = v;
            }
        }
    }
}

// ---------------------------------------------------------------------------
// Fused branch-MLP GEMM (R8-R12 proven): all 5 source-depth levels in ONE
// 3664-block dispatch at 128^2 tiles (s=0: 1x80, s=1: 2x64, s=2: 8x48,
// s=3: 32x32, s=4: 128x16). K=512 for all.
// ---------------------------------------------------------------------------
__global__ __launch_bounds__(256) void gemm_branch_fused(
    const __hip_bfloat16* __restrict__ xn, const __hip_bfloat16* __restrict__ wcat,
    __hip_bfloat16* __restrict__ Y) {
    __shared__ __hip_bfloat16 As[128 * 64];
    __shared__ __hip_bfloat16 Bs[128 * 64];
    const int lin = xcd_remap(blockIdx.x, gridDim.x);
    int s;
    if (lin < 80)        s = 0;
    else if (lin < 208)  s = 1;
    else if (lin < 592)  s = 2;
    else if (lin < 1616) s = 3;
    else                 s = 4;
    const int base_tab[5] = {0, 80, 208, 592, 1616};
    const int gn_tab[5]   = {80, 64, 48, 32, 16};
    const size_t yoff[5]  = {0, 655360, 2752512, 9043968, 25821184};
    const int wcat_off[5] = {0, 5, 9, 12, 14};
    const int loc = lin - base_tab[s];
    const int gn = gn_tab[s];
    const int bx = loc / gn;              // A-major within each s
    const int by = loc - bx * gn;
    const int Mrows = 64 << (s << 1);
    const int N = (5 - s) << 11;
    gemm128_body<true>(As, Bs, xn, wcat + (size_t)wcat_off[s] * (2048ull * 512),
                       nullptr, nullptr, nullptr, Y + yoff[s],
                       Mrows, N, 512, GF_OUTBF16, s, bx << 7, by << 7);
}

// ---------------------------------------------------------------------------
extern "C" void kernel_launch(void* const* d_in, const int* in_sizes, int n_in,
                              void* d_out, int out_size, void* d_ws, size_t ws_size,
                              hipStream_t stream) {
    const float* x      = (const float*)d_in[0];
    const float* ln1_g  = (const float*)d_in[1];
    const float* ln1_b  = (const float*)d_in[2];
    const float* w_qkv  = (const float*)d_in[3];
    const float* b_qkv  = (const float*)d_in[4];
    const float* w_proj = (const float*)d_in[5];
    const float* b_proj = (const float*)d_in[6];
    const float* ln2_g  = (const float*)d_in[7];
    const float* ln2_b  = (const float*)d_in[8];
    const float* mlp_M  = (const float*)d_in[9];
    const float* mlp_b1 = (const float*)d_in[10];
    const float* w2     = (const float*)d_in[11];
    const float* b2     = (const float*)d_in[12];
    float* out = (float*)d_out;

    const int M = 64 * 341;  // 21824 rows

    char* ws = (char*)d_ws;
    size_t off = 0;
    auto alloc = [&](size_t bytes) -> char* {
        char* p = ws + off;
        off += (bytes + 255) & ~(size_t)255;
        return p;
    };
    __hip_bfloat16* xn     = (__hip_bfloat16*)alloc((size_t)M * 512 * 2);
    __hip_bfloat16* wqkvT  = (__hip_bfloat16*)alloc(1536ull * 512 * 2);
    __hip_bfloat16* wprojT = (__hip_bfloat16*)alloc(512ull * 512 * 2);
    __hip_bfloat16* w2T    = (__hip_bfloat16*)alloc(512ull * 2048 * 2);
    __hip_bfloat16* wcat   = (__hip_bfloat16*)alloc(15ull * 2048 * 512 * 2);
    // shared region: qkv+ctx (attention phase) overlaid by Y (branch phase)
    const size_t qkv_bytes = (size_t)M * 1536 * 2;            // 67,043,328
    const size_t y_bytes   = 59375616ull * 2;                 // 118,751,232
    char* shared = alloc(y_bytes);                            // >= qkv+ctx
    __hip_bfloat16* qkv = (__hip_bfloat16*)shared;
    __hip_bfloat16* ctx = (__hip_bfloat16*)(shared + qkv_bytes);
    __hip_bfloat16* Y   = (__hip_bfloat16*)shared;
    if (off > ws_size) return;  // workspace too small -> clean validation failure

    auto g128 = [&](const __hip_bfloat16* A, const __hip_bfloat16* Bt,
                    const float* bias, const float* resid, float* Cf,
                    __hip_bfloat16* Cb, int Mr, int N, int K, int flags) {
        int gm = (Mr + 127) >> 7, gn = N >> 7;
        gemm128<<<dim3(gm * gn), 256, 0, stream>>>(
            A, Bt, bias, resid, Cf, Cb, Mr, N, K, flags, gn);
    };
    auto g64 = [&](const __hip_bfloat16* A, const __hip_bfloat16* Bt,
                   const float* bias, const float* resid, float* Cf,
                   __hip_bfloat16* Cb, int Mr, int N, int K, int flags) {
        int gm = (Mr + 63) >> 6, gn = N >> 7;
        gemm64<<<dim3(gm * gn), 256, 0, stream>>>(
            A, Bt, bias, resid, Cf, Cb, Mr, N, K, flags, gn);
    };

    // weight prep
    transpose_bf16_kernel<<<(512 * 1536 + 255) / 256, 256, 0, stream>>>(w_qkv, wqkvT, 512, 1536, 9);
    transpose_bf16_kernel<<<(512 * 512 + 255) / 256, 256, 0, stream>>>(w_proj, wprojT, 512, 512, 9);
    transpose_bf16_kernel<<<(2048 * 512 + 255) / 256, 256, 0, stream>>>(w2, w2T, 2048, 512, 11);
    pack_wcat_kernel<<<dim3(4096, 15), 256, 0, stream>>>(mlp_M, wcat);

    // attention path
    ln_kernel<<<M, 256, 0, stream>>>(x, ln1_g, ln1_b, xn);
    g128(xn, wqkvT, b_qkv, nullptr, nullptr, qkv, M, 1536, 512, GF_OUTBF16);
    attn_mfma_kernel<<<dim3(512, 2), 256, 0, stream>>>(qkv, ctx);
    g64(ctx, wprojT, b_proj, x, out, nullptr, M, 512, 512, 0);

    // branch MLP path: Y_s GEMMs (dedup) then w2 with fused combine
    ln_kernel<<<M, 256, 0, stream>>>(out, ln2_g, ln2_b, xn);
    gemm_branch_fused<<<dim3(3664), 256, 0, stream>>>(xn, wcat, Y);
    gemm64_w2<<<dim3(1364), 256, 0, stream>>>(Y, mlp_b1, w2T, b2, out, 4);
}

// Round 10
// 701.902 us; speedup vs baseline: 1.1062x; 1.1062x over previous
//
#include <hip/hip_runtime.h>
#include <hip/hip_bf16.h>

// ---------------------------------------------------------------------------
// Treensformer block: x += MHSA(LN1(x)); x += BranchMLP(LN2(x))
// B=64, N_NODES=341, E=512, H=8, hd=64, 4*E=2048, N_LEVELS=4
// R1: MFMA flash attention. R5: branch-MLP ancestor dedup.
// R6/R7: 256^2 deep pipeline -> REGRESSED. R8: 128^2 + fused branch +
//     XCD/A-major remap: 785us. R9: BK64 + XOR swizzle: 751 (conflicts->0).
// R10: gemm64 for proj/w2: 722 (residency mechanism: 72 regs -> 6 blk/CU
//     vs gemm128's 136 -> 3; pays only when grid deeper than residency).
// R11: split-K: REGRESSED. R12: launch_bounds(256,6): ~neutral (w2 121).
// R13: gemm64 for qkv AND branch: net +20, decomposed as branch +26
//     (REGRESSED: grid already 14/CU deep; tile halving only doubled
//     B-amplification) and qkv ~-6 (WIN: same mechanism as R10).
// R14: combine fused into w2 A-staging: REGRESSED HARD (w2 path 166 ->
//     260us; VALUBusy 21%, MfmaUtil 7.1: ~13 loads + ~90 VALU per thread
//     per iteration inside the 2-barrier lockstep chain). Lesson: staging-
//     path fusion only viable for near-zero-cost transforms. REVERTED.
// R15: best-of-each measured assembly: qkv -> gemm64 (R13-isolated -6us),
//     branch -> gemm128 (R12-proven), proj/w2 -> gemm64 (R10-proven),
//     separate combine (R14-proven) + XCD-chunked remap on combine
//     (consecutive rows = same batch share ancestor Y segments; chunking
//     localizes them to one XCD's L2; logical Y reads ~447MB vs 119MB
//     unique -> real reuse to localize). Addressing-only changes.
// ---------------------------------------------------------------------------

typedef __attribute__((ext_vector_type(8))) __bf16 bf16x8;
typedef __attribute__((ext_vector_type(4))) float f32x4;
typedef __attribute__((ext_vector_type(4))) unsigned int u32x4;

#define GF_RELU    1
#define GF_OUTBF16 2

static __device__ __forceinline__ bf16x8 bzero8() {
    u32x4 z = {0u, 0u, 0u, 0u};
    return __builtin_bit_cast(bf16x8, z);
}

// ---------------------------------------------------------------------------
// Weight transpose+convert: out[n*K + k] = bf16(in[k*N + n]); K is pow2.
// ---------------------------------------------------------------------------
__global__ void transpose_bf16_kernel(const float* __restrict__ in,
                                      __hip_bfloat16* __restrict__ out,
                                      int K, int N, int log2K) {
    int idx = blockIdx.x * 256 + threadIdx.x;
    if (idx >= K * N) return;
    int n = idx >> log2K;
    int k = idx & (K - 1);
    out[idx] = __float2bfloat16(in[(size_t)k * N + n]);
}

// ---------------------------------------------------------------------------
// Pack mlp_M (5,5,2048,512) fp32 -> Wcat bf16 grouped by source depth s.
// ---------------------------------------------------------------------------
__global__ void pack_wcat_kernel(const float* __restrict__ M,
                                 __hip_bfloat16* __restrict__ out) {
    int p = blockIdx.y;
    int s, d;
    if (p < 5)       { s = 0; d = p; }
    else if (p < 9)  { s = 1; d = p - 4; }
    else if (p < 12) { s = 2; d = p - 7; }
    else if (p < 14) { s = 3; d = p - 9; }
    else             { s = 4; d = 4; }
    const int base_lut[5] = {0, 5, 9, 12, 14};
    size_t idx = (size_t)blockIdx.x * 256 + threadIdx.x;  // 0 .. 2048*512-1
    const size_t MB = 2048ull * 512;
    out[(size_t)base_lut[s] * MB + (size_t)(d - s) * MB + idx] =
        __float2bfloat16(M[((size_t)d * 5 + s) * MB + idx]);
}

// ---------------------------------------------------------------------------
// LayerNorm over E=512, one block (256 threads) per token; writes bf16.
// ---------------------------------------------------------------------------
__global__ __launch_bounds__(256) void ln_kernel(const float* __restrict__ x,
                                                 const float* __restrict__ g,
                                                 const float* __restrict__ b,
                                                 __hip_bfloat16* __restrict__ out) {
    int tok = blockIdx.x;
    const float* xr = x + (size_t)tok * 512;
    int t = threadIdx.x;
    float v0 = xr[t], v1 = xr[t + 256];
    float s = v0 + v1;
    float s2 = v0 * v0 + v1 * v1;
    #pragma unroll
    for (int o = 32; o > 0; o >>= 1) {
        s  += __shfl_down(s, o);
        s2 += __shfl_down(s2, o);
    }
    __shared__ float ps[4], ps2[4];
    int w = t >> 6, lane = t & 63;
    if (lane == 0) { ps[w] = s; ps2[w] = s2; }
    __syncthreads();
    if (t == 0) {
        float ts = 0.f, ts2 = 0.f;
        #pragma unroll
        for (int i = 0; i < 4; i++) { ts += ps[i]; ts2 += ps2[i]; }
        ps[0] = ts * (1.f / 512.f);
        ps2[0] = ts2 * (1.f / 512.f);
    }
    __syncthreads();
    float m = ps[0];
    float var = ps2[0] - m * m;
    float r = rsqrtf(var + 1e-5f);
    out[(size_t)tok * 512 + t]       = __float2bfloat16((v0 - m) * r * g[t] + b[t]);
    out[(size_t)tok * 512 + t + 256] = __float2bfloat16((v1 - m) * r * g[t + 256] + b[t + 256]);
}

// ---------------------------------------------------------------------------
// MFMA flash attention (unchanged from R2).
// ---------------------------------------------------------------------------
#define ATT_STR 72
__global__ __launch_bounds__(256) void attn_mfma_kernel(const __hip_bfloat16* __restrict__ qkv,
                                                        __hip_bfloat16* __restrict__ ctx) {
    __shared__ __bf16 kt_lds[64 * ATT_STR];
    __shared__ __bf16 vt_lds[64 * ATT_STR];
    __shared__ __bf16 pbuf[4 * 48 * ATT_STR];

    const int bh = blockIdx.x;
    const int half = blockIdx.y;
    const int b = bh >> 3, h = bh & 7;
    const int tid = threadIdx.x;
    const int w = tid >> 6, lane = tid & 63;
    const int q = lane >> 4, l16 = lane & 15;
    const int rowbase = half * 192 + w * 48;
    __bf16* pw = pbuf + w * 48 * ATT_STR;

    bf16x8 qf[3][2];
    #pragma unroll
    for (int mi = 0; mi < 3; mi++) {
        int row = rowbase + mi * 16 + l16;
        #pragma unroll
        for (int ks = 0; ks < 2; ks++) {
            if (row < 341)
                qf[mi][ks] = *(const bf16x8*)(qkv + (size_t)(b * 341 + row) * 1536 +
                                              h * 64 + ks * 32 + q * 8);
            else
                qf[mi][ks] = bzero8();
        }
    }

    f32x4 O[3][4];
    float mrun[3][4], lrun[3][4];
    #pragma unroll
    for (int mi = 0; mi < 3; mi++) {
        #pragma unroll
        for (int ni = 0; ni < 4; ni++) { f32x4 z = {0.f,0.f,0.f,0.f}; O[mi][ni] = z; }
        #pragma unroll
        for (int rr = 0; rr < 4; rr++) { mrun[mi][rr] = -1e30f; lrun[mi][rr] = 0.f; }
    }

    for (int kt6 = 0; kt6 < 6; kt6++) {
        const int kbase = kt6 * 64;
        __syncthreads();
        {
            int key = tid >> 2, kg = tid & 3;
            int gk = kbase + key;
            bf16x8 a0 = bzero8(), a1 = bzero8();
            if (gk < 341) {
                const __hip_bfloat16* src =
                    qkv + (size_t)(b * 341 + gk) * 1536 + 512 + h * 64 + kg * 16;
                a0 = *(const bf16x8*)src;
                a1 = *(const bf16x8*)(src + 8);
            }
            *(bf16x8*)(kt_lds + key * ATT_STR + kg * 16)     = a0;
            *(bf16x8*)(kt_lds + key * ATT_STR + kg * 16 + 8) = a1;
        }
        {
            int key = tid & 63, dg = tid >> 6;
            int gk = kbase + key;
            bf16x8 a0 = bzero8(), a1 = bzero8();
            if (gk < 341) {
                const __hip_bfloat16* src =
                    qkv + (size_t)(b * 341 + gk) * 1536 + 1024 + h * 64 + dg * 16;
                a0 = *(const bf16x8*)src;
                a1 = *(const bf16x8*)(src + 8);
            }
            #pragma unroll
            for (int j = 0; j < 8; j++) {
                vt_lds[(dg * 16 + j) * ATT_STR + key]     = a0[j];
                vt_lds[(dg * 16 + 8 + j) * ATT_STR + key] = a1[j];
            }
        }
        __syncthreads();

        f32x4 S[3][4];
        #pragma unroll
        for (int mi = 0; mi < 3; mi++)
            #pragma unroll
            for (int ni = 0; ni < 4; ni++) { f32x4 z = {0.f,0.f,0.f,0.f}; S[mi][ni] = z; }
        #pragma unroll
        for (int ks = 0; ks < 2; ks++) {
            bf16x8 bf_[4];
            #pragma unroll
            for (int ni = 0; ni < 4; ni++)
                bf_[ni] = *(const bf16x8*)(kt_lds + (ni * 16 + l16) * ATT_STR + ks * 32 + q * 8);
            #pragma unroll
            for (int mi = 0; mi < 3; mi++)
                #pragma unroll
                for (int ni = 0; ni < 4; ni++)
                    S[mi][ni] = __builtin_amdgcn_mfma_f32_16x16x32_bf16(qf[mi][ks], bf_[ni],
                                                                        S[mi][ni], 0, 0, 0);
        }

        float cmask[4];
        #pragma unroll
        for (int ni = 0; ni < 4; ni++)
            cmask[ni] = (kbase + ni * 16 + l16 < 341) ? 0.f : -1e30f;

        #pragma unroll
        for (int mi = 0; mi < 3; mi++) {
            #pragma unroll
            for (int rr = 0; rr < 4; rr++) {
                float rmax = -1e30f;
                #pragma unroll
                for (int ni = 0; ni < 4; ni++)
                    rmax = fmaxf(rmax, fmaf(S[mi][ni][rr], 0.125f, cmask[ni]));
                rmax = fmaxf(rmax, __shfl_xor(rmax, 1));
                rmax = fmaxf(rmax, __shfl_xor(rmax, 2));
                rmax = fmaxf(rmax, __shfl_xor(rmax, 4));
                rmax = fmaxf(rmax, __shfl_xor(rmax, 8));
                float mnew = fmaxf(mrun[mi][rr], rmax);
                float alpha = __expf(mrun[mi][rr] - mnew);
                mrun[mi][rr] = mnew;
                float psum = 0.f;
                #pragma unroll
                for (int ni = 0; ni < 4; ni++) {
                    float p = __expf(fmaf(S[mi][ni][rr], 0.125f, cmask[ni]) - mnew);
                    S[mi][ni][rr] = p;
                    psum += p;
                    O[mi][ni][rr] *= alpha;
                }
                psum += __shfl_xor(psum, 1);
                psum += __shfl_xor(psum, 2);
                psum += __shfl_xor(psum, 4);
                psum += __shfl_xor(psum, 8);
                lrun[mi][rr] = lrun[mi][rr] * alpha + psum;
            }
            #pragma unroll
            for (int ni = 0; ni < 4; ni++)
                #pragma unroll
                for (int rr = 0; rr < 4; rr++)
                    pw[(mi * 16 + q * 4 + rr) * ATT_STR + ni * 16 + l16] =
                        (__bf16)S[mi][ni][rr];
        }
        __syncthreads();

        #pragma unroll
        for (int ks = 0; ks < 2; ks++) {
            bf16x8 pf[3], vf[4];
            #pragma unroll
            for (int mi = 0; mi < 3; mi++)
                pf[mi] = *(const bf16x8*)(pw + (mi * 16 + l16) * ATT_STR + ks * 32 + q * 8);
            #pragma unroll
            for (int ni = 0; ni < 4; ni++)
                vf[ni] = *(const bf16x8*)(vt_lds + (ni * 16 + l16) * ATT_STR + ks * 32 + q * 8);
            #pragma unroll
            for (int mi = 0; mi < 3; mi++)
                #pragma unroll
                for (int ni = 0; ni < 4; ni++)
                    O[mi][ni] = __builtin_amdgcn_mfma_f32_16x16x32_bf16(pf[mi], vf[ni],
                                                                        O[mi][ni], 0, 0, 0);
        }
    }

    #pragma unroll
    for (int mi = 0; mi < 3; mi++) {
        #pragma unroll
        for (int rr = 0; rr < 4; rr++) {
            int row = rowbase + mi * 16 + q * 4 + rr;
            if (row >= 341) continue;
            float inv = 1.f / lrun[mi][rr];
            __hip_bfloat16* op = ctx + (size_t)(b * 341 + row) * 512 + h * 64;
            #pragma unroll
            for (int ni = 0; ni < 4; ni++)
                op[ni * 16 + l16] = __float2bfloat16(O[mi][ni][rr] * inv);
        }
    }
}

// bijective XCD-aware remap (m204): each XCD gets a contiguous chunk of the
// logical (A-major) tile order -> neighboring tiles sharing an A row-panel
// land on the same XCD's L2.
static __device__ __forceinline__ int xcd_remap(int bid, int nwg) {
    const int xcd = bid & 7, o = bid >> 3;
    const int qq = nwg >> 3, rr = nwg & 7;
    return (xcd < rr ? xcd * (qq + 1) : rr * (qq + 1) + (xcd - rr) * qq) + o;
}

// ---------------------------------------------------------------------------
// gemm128 body (128x128xBK64, register staging, both-sides XOR swizzle).
// Used by the fused branch GEMM only (deep grid, 3 blk/CU residency is
// sufficient there; R13 proved 64x128 hurts it).
// ---------------------------------------------------------------------------
template <bool GATHER>
static __device__ __forceinline__ void gemm128_body(
    __hip_bfloat16* As, __hip_bfloat16* Bs,
    const __hip_bfloat16* __restrict__ A, const __hip_bfloat16* __restrict__ Bt,
    const float* __restrict__ bias, const float* __restrict__ resid,
    float* __restrict__ Cf, __hip_bfloat16* __restrict__ Cb,
    int Mrows, int N, int K, int flags, int depth, int bm0, int bn0) {
    const int tid = threadIdx.x;
    const int r = tid >> 1;            // staging row 0..127
    const int khalf = tid & 1;         // 0/1 -> 32-element (64B) half of row
    const int gr = bm0 + r;
    const int gn = bn0 + r;
    const int lane = tid & 63;
    const int w = tid >> 6;
    const int wm = (w >> 1) << 6;
    const int wn = (w & 1) << 6;
    const int q = lane >> 4;
    const int l16 = lane & 15;

    int wsl[4];
    #pragma unroll
    for (int j = 0; j < 4; j++)
        wsl[j] = ((((khalf << 2) | j) ^ (r & 7)) << 3);
    const int rs0 = ((q ^ (l16 & 7)) << 3);
    const int rs1 = (((4 + q) ^ (l16 & 7)) << 3);

    size_t abase;
    if (GATHER) {
        const int dsh = depth << 1;
        const int bmask = (1 << dsh) - 1;
        int b = gr >> dsh;
        int i = gr & bmask;
        int node = (0x55555555 & bmask) + i;   // offs[depth] + i
        abase = ((size_t)(b * 341 + node)) << 9;
    } else {
        abase = (size_t)gr * K;
    }

    f32x4 acc[4][4];
    #pragma unroll
    for (int i = 0; i < 4; i++)
        #pragma unroll
        for (int j = 0; j < 4; j++) {
            f32x4 z = {0.f, 0.f, 0.f, 0.f};
            acc[i][j] = z;
        }

    for (int k0 = 0; k0 < K; k0 += 64) {
        bf16x8 va[4], vb[4];
        if (gr < Mrows) {
            const bf16x8* p = (const bf16x8*)(A + abase + k0 + (khalf << 5));
            #pragma unroll
            for (int j = 0; j < 4; j++) va[j] = p[j];
        } else {
            #pragma unroll
            for (int j = 0; j < 4; j++) va[j] = bzero8();
        }
        {
            const bf16x8* p = (const bf16x8*)(Bt + (size_t)gn * K + k0 + (khalf << 5));
            #pragma unroll
            for (int j = 0; j < 4; j++) vb[j] = p[j];
        }
        __syncthreads();  // previous iteration's fragment reads complete
        #pragma unroll
        for (int j = 0; j < 4; j++) {
            *(bf16x8*)(As + r * 64 + wsl[j]) = va[j];
            *(bf16x8*)(Bs + r * 64 + wsl[j]) = vb[j];
        }
        __syncthreads();
        bf16x8 af[4][2], bfr[4][2];
        #pragma unroll
        for (int mi = 0; mi < 4; mi++) {
            const __hip_bfloat16* rp = As + (wm + mi * 16 + l16) * 64;
            af[mi][0] = *(const bf16x8*)(rp + rs0);
            af[mi][1] = *(const bf16x8*)(rp + rs1);
        }
        #pragma unroll
        for (int ni = 0; ni < 4; ni++) {
            const __hip_bfloat16* rp = Bs + (wn + ni * 16 + l16) * 64;
            bfr[ni][0] = *(const bf16x8*)(rp + rs0);
            bfr[ni][1] = *(const bf16x8*)(rp + rs1);
        }
        #pragma unroll
        for (int ks = 0; ks < 2; ks++)
            #pragma unroll
            for (int mi = 0; mi < 4; mi++)
                #pragma unroll
                for (int ni = 0; ni < 4; ni++)
                    acc[mi][ni] = __builtin_amdgcn_mfma_f32_16x16x32_bf16(
                        af[mi][ks], bfr[ni][ks], acc[mi][ni], 0, 0, 0);
    }

    #pragma unroll
    for (int mi = 0; mi < 4; mi++) {
        #pragma unroll
        for (int rr = 0; rr < 4; rr++) {
            int grow = bm0 + wm + mi * 16 + q * 4 + rr;
            if (grow >= Mrows) continue;
            size_t obase = (size_t)grow * N;
            #pragma unroll
            for (int ni = 0; ni < 4; ni++) {
                int col = bn0 + wn + ni * 16 + l16;
                float v = acc[mi][ni][rr];
                if (bias) v += bias[col];
                if (resid) v += resid[obase + col];
                if (flags & GF_RELU) v = fmaxf(v, 0.f);
                if (flags & GF_OUTBF16)
                    Cb[obase + col] = __float2bfloat16(v);
                else
                    Cf[obase + col] = v;
            }
        }
    }
}

// ---------------------------------------------------------------------------
// gemm64: 64(M)x128(N)xBK64 for qkv, proj, w2. 256 threads = 4 waves, each
// wave 64x32 (acc[4][2] = 32 AGPR; ~72 unified regs -> 6 blocks/CU with
// 24KB LDS). Register staging + both-sides XOR slot swizzle (R9/R10).
// ---------------------------------------------------------------------------
__global__ __launch_bounds__(256, 6) void gemm64(
    const __hip_bfloat16* __restrict__ A, const __hip_bfloat16* __restrict__ Bt,
    const float* __restrict__ bias, const float* __restrict__ resid,
    float* __restrict__ Cf, __hip_bfloat16* __restrict__ Cb,
    int Mrows, int N, int K, int flags, int gridN) {
    __shared__ __hip_bfloat16 As[64 * 64];
    __shared__ __hip_bfloat16 Bs[128 * 64];
    const int lin = xcd_remap(blockIdx.x, gridDim.x);
    const int bx = lin / gridN;           // A-major
    const int by = lin - bx * gridN;
    const int bm0 = bx << 6, bn0 = by << 7;

    const int tid = threadIdx.x;
    const int ra = tid >> 2, kq = tid & 3;      // A: 4 threads/row, 2 slots
    const int rb = tid >> 1, khalf = tid & 1;   // B: 2 threads/row, 4 slots
    const int lane = tid & 63;
    const int w = tid >> 6;
    const int wn = w << 5;                      // wave col offset 0/32/64/96
    const int q = lane >> 4;
    const int l16 = lane & 15;

    const int gra = bm0 + ra;
    const int gnb = bn0 + rb;

    int wslA[2];
    #pragma unroll
    for (int j = 0; j < 2; j++)
        wslA[j] = ((((kq << 1) | j) ^ (ra & 7)) << 3);
    int wslB[4];
    #pragma unroll
    for (int j = 0; j < 4; j++)
        wslB[j] = ((((khalf << 2) | j) ^ (rb & 7)) << 3);
    const int rs0 = ((q ^ (l16 & 7)) << 3);
    const int rs1 = (((4 + q) ^ (l16 & 7)) << 3);

    const size_t abase = (size_t)gra * K;

    f32x4 acc[4][2];
    #pragma unroll
    for (int i = 0; i < 4; i++)
        #pragma unroll
        for (int j = 0; j < 2; j++) {
            f32x4 z = {0.f, 0.f, 0.f, 0.f};
            acc[i][j] = z;
        }

    for (int k0 = 0; k0 < K; k0 += 64) {
        bf16x8 va[2], vb[4];
        if (gra < Mrows) {
            const bf16x8* p = (const bf16x8*)(A + abase + k0 + (kq << 4));
            #pragma unroll
            for (int j = 0; j < 2; j++) va[j] = p[j];
        } else {
            #pragma unroll
            for (int j = 0; j < 2; j++) va[j] = bzero8();
        }
        {
            const bf16x8* p = (const bf16x8*)(Bt + (size_t)gnb * K + k0 + (khalf << 5));
            #pragma unroll
            for (int j = 0; j < 4; j++) vb[j] = p[j];
        }
        __syncthreads();  // previous iteration's fragment reads complete
        #pragma unroll
        for (int j = 0; j < 2; j++)
            *(bf16x8*)(As + ra * 64 + wslA[j]) = va[j];
        #pragma unroll
        for (int j = 0; j < 4; j++)
            *(bf16x8*)(Bs + rb * 64 + wslB[j]) = vb[j];
        __syncthreads();
        bf16x8 af[4][2], bfr[2][2];
        #pragma unroll
        for (int mi = 0; mi < 4; mi++) {
            const __hip_bfloat16* rp = As + (mi * 16 + l16) * 64;
            af[mi][0] = *(const bf16x8*)(rp + rs0);
            af[mi][1] = *(const bf16x8*)(rp + rs1);
        }
        #pragma unroll
        for (int ni = 0; ni < 2; ni++) {
            const __hip_bfloat16* rp = Bs + (wn + ni * 16 + l16) * 64;
            bfr[ni][0] = *(const bf16x8*)(rp + rs0);
            bfr[ni][1] = *(const bf16x8*)(rp + rs1);
        }
        #pragma unroll
        for (int ks = 0; ks < 2; ks++)
            #pragma unroll
            for (int mi = 0; mi < 4; mi++)
                #pragma unroll
                for (int ni = 0; ni < 2; ni++)
                    acc[mi][ni] = __builtin_amdgcn_mfma_f32_16x16x32_bf16(
                        af[mi][ks], bfr[ni][ks], acc[mi][ni], 0, 0, 0);
    }

    #pragma unroll
    for (int mi = 0; mi < 4; mi++) {
        #pragma unroll
        for (int rr = 0; rr < 4; rr++) {
            int grow = bm0 + mi * 16 + q * 4 + rr;
            if (grow >= Mrows) continue;
            size_t obase = (size_t)grow * N;
            #pragma unroll
            for (int ni = 0; ni < 2; ni++) {
                int col = bn0 + wn + ni * 16 + l16;
                float v = acc[mi][ni][rr];
                if (bias) v += bias[col];
                if (resid) v += resid[obase + col];
                if (flags & GF_RELU) v = fmaxf(v, 0.f);
                if (flags & GF_OUTBF16)
                    Cb[obase + col] = __float2bfloat16(v);
                else
                    Cf[obase + col] = v;
            }
        }
    }
}

// ---------------------------------------------------------------------------
// Fused branch-MLP GEMM (R8-R12 proven): all 5 source-depth levels in ONE
// 3664-block dispatch at 128^2 tiles (s=0: 1x80, s=1: 2x64, s=2: 8x48,
// s=3: 32x32, s=4: 128x16). K=512 for all.
// ---------------------------------------------------------------------------
__global__ __launch_bounds__(256) void gemm_branch_fused(
    const __hip_bfloat16* __restrict__ xn, const __hip_bfloat16* __restrict__ wcat,
    __hip_bfloat16* __restrict__ Y) {
    __shared__ __hip_bfloat16 As[128 * 64];
    __shared__ __hip_bfloat16 Bs[128 * 64];
    const int lin = xcd_remap(blockIdx.x, gridDim.x);
    int s;
    if (lin < 80)        s = 0;
    else if (lin < 208)  s = 1;
    else if (lin < 592)  s = 2;
    else if (lin < 1616) s = 3;
    else                 s = 4;
    const int base_tab[5] = {0, 80, 208, 592, 1616};
    const int gn_tab[5]   = {80, 64, 48, 32, 16};
    const size_t yoff[5]  = {0, 655360, 2752512, 9043968, 25821184};
    const int wcat_off[5] = {0, 5, 9, 12, 14};
    const int loc = lin - base_tab[s];
    const int gn = gn_tab[s];
    const int bx = loc / gn;              // A-major within each s
    const int by = loc - bx * gn;
    const int Mrows = 64 << (s << 1);
    const int N = (5 - s) << 11;
    gemm128_body<true>(As, Bs, xn, wcat + (size_t)wcat_off[s] * (2048ull * 512),
                       nullptr, nullptr, nullptr, Y + yoff[s],
                       Mrows, N, 512, GF_OUTBF16, s, bx << 7, by << 7);
}

// ---------------------------------------------------------------------------
// Combine: h[b,node@d,:] = ReLU( sum_{s<=d} Y_s[...] + b1[node] ).
// R15: XCD-chunked remap — consecutive rows (same batch) share ancestor
// Y segments; chunking keeps a batch's shared segments in one XCD's L2.
// ---------------------------------------------------------------------------
__global__ __launch_bounds__(256) void combine_kernel(const __hip_bfloat16* __restrict__ Y,
                                                      const float* __restrict__ b1,
                                                      __hip_bfloat16* __restrict__ h) {
    const size_t yoff[5] = {0, 655360, 2752512, 9043968, 25821184};
    int row = xcd_remap(blockIdx.x, gridDim.x);
    int b = row / 341;
    int node = row - b * 341;
    int d = (node >= 85) ? 4 : (node >= 21) ? 3 : (node >= 5) ? 2 : (node >= 1) ? 1 : 0;
    int i = node - (0x55555555 & ((1 << (d << 1)) - 1));
    int j = threadIdx.x << 3;

    float acc[8];
    const float* bp = b1 + (size_t)node * 2048 + j;
    f32x4 b0 = *(const f32x4*)bp;
    f32x4 b4 = *(const f32x4*)(bp + 4);
    #pragma unroll
    for (int u = 0; u < 4; u++) { acc[u] = b0[u]; acc[u + 4] = b4[u]; }

    #pragma unroll
    for (int s = 0; s < 5; s++) {
        if (s <= d) {
            int a = i >> ((d - s) << 1);
            int width = (5 - s) << 11;
            const bf16x8 v = *(const bf16x8*)(Y + yoff[s] +
                (size_t)((b << (s << 1)) + a) * width + ((d - s) << 11) + j);
            #pragma unroll
            for (int u = 0; u < 8; u++) acc[u] += (float)v[u];
        }
    }
    bf16x8 o;
    #pragma unroll
    for (int u = 0; u < 8; u++) o[u] = (__bf16)fmaxf(acc[u], 0.f);
    *(bf16x8*)(h + (size_t)row * 2048 + j) = o;
}

// ---------------------------------------------------------------------------
extern "C" void kernel_launch(void* const* d_in, const int* in_sizes, int n_in,
                              void* d_out, int out_size, void* d_ws, size_t ws_size,
                              hipStream_t stream) {
    const float* x      = (const float*)d_in[0];
    const float* ln1_g  = (const float*)d_in[1];
    const float* ln1_b  = (const float*)d_in[2];
    const float* w_qkv  = (const float*)d_in[3];
    const float* b_qkv  = (const float*)d_in[4];
    const float* w_proj = (const float*)d_in[5];
    const float* b_proj = (const float*)d_in[6];
    const float* ln2_g  = (const float*)d_in[7];
    const float* ln2_b  = (const float*)d_in[8];
    const float* mlp_M  = (const float*)d_in[9];
    const float* mlp_b1 = (const float*)d_in[10];
    const float* w2     = (const float*)d_in[11];
    const float* b2     = (const float*)d_in[12];
    float* out = (float*)d_out;

    const int M = 64 * 341;  // 21824 rows

    char* ws = (char*)d_ws;
    size_t off = 0;
    auto alloc = [&](size_t bytes) -> char* {
        char* p = ws + off;
        off += (bytes + 255) & ~(size_t)255;
        return p;
    };
    __hip_bfloat16* xn     = (__hip_bfloat16*)alloc((size_t)M * 512 * 2);
    __hip_bfloat16* wqkvT  = (__hip_bfloat16*)alloc(1536ull * 512 * 2);
    __hip_bfloat16* wprojT = (__hip_bfloat16*)alloc(512ull * 512 * 2);
    __hip_bfloat16* w2T    = (__hip_bfloat16*)alloc(512ull * 2048 * 2);
    __hip_bfloat16* wcat   = (__hip_bfloat16*)alloc(15ull * 2048 * 512 * 2);
    __hip_bfloat16* hbuf   = (__hip_bfloat16*)alloc((size_t)M * 2048 * 2);
    // shared region: qkv+ctx (attention phase) overlaid by Y (branch phase)
    const size_t qkv_bytes = (size_t)M * 1536 * 2;            // 67,043,328
    const size_t y_bytes   = 59375616ull * 2;                 // 118,751,232
    char* shared = alloc(y_bytes);                            // >= qkv+ctx
    __hip_bfloat16* qkv = (__hip_bfloat16*)shared;
    __hip_bfloat16* ctx = (__hip_bfloat16*)(shared + qkv_bytes);
    __hip_bfloat16* Y   = (__hip_bfloat16*)shared;
    if (off > ws_size) return;  // workspace too small -> clean validation failure

    auto g64 = [&](const __hip_bfloat16* A, const __hip_bfloat16* Bt,
                   const float* bias, const float* resid, float* Cf,
                   __hip_bfloat16* Cb, int Mr, int N, int K, int flags) {
        int gm = (Mr + 63) >> 6, gn = N >> 7;
        gemm64<<<dim3(gm * gn), 256, 0, stream>>>(
            A, Bt, bias, resid, Cf, Cb, Mr, N, K, flags, gn);
    };

    // weight prep
    transpose_bf16_kernel<<<(512 * 1536 + 255) / 256, 256, 0, stream>>>(w_qkv, wqkvT, 512, 1536, 9);
    transpose_bf16_kernel<<<(512 * 512 + 255) / 256, 256, 0, stream>>>(w_proj, wprojT, 512, 512, 9);
    transpose_bf16_kernel<<<(2048 * 512 + 255) / 256, 256, 0, stream>>>(w2, w2T, 2048, 512, 11);
    pack_wcat_kernel<<<dim3(4096, 15), 256, 0, stream>>>(mlp_M, wcat);

    // attention path (qkv now on gemm64: R13-isolated -6us win)
    ln_kernel<<<M, 256, 0, stream>>>(x, ln1_g, ln1_b, xn);
    g64(xn, wqkvT, b_qkv, nullptr, nullptr, qkv, M, 1536, 512, GF_OUTBF16);
    attn_mfma_kernel<<<dim3(512, 2), 256, 0, stream>>>(qkv, ctx);
    g64(ctx, wprojT, b_proj, x, out, nullptr, M, 512, 512, 0);

    // branch MLP path (dedup by source depth s) — single fused dispatch
    ln_kernel<<<M, 256, 0, stream>>>(out, ln2_g, ln2_b, xn);
    gemm_branch_fused<<<dim3(3664), 256, 0, stream>>>(xn, wcat, Y);
    combine_kernel<<<M, 256, 0, stream>>>(Y, mlp_b1, hbuf);
    g64(hbuf, w2T, b2, out, out, nullptr, M, 512, 2048, 0);
}

// Round 11
// 691.326 us; speedup vs baseline: 1.1231x; 1.0153x over previous
//
#include <hip/hip_runtime.h>
#include <hip/hip_bf16.h>

// ---------------------------------------------------------------------------
// Treensformer block: x += MHSA(LN1(x)); x += BranchMLP(LN2(x))
// B=64, N_NODES=341, E=512, H=8, hd=64, 4*E=2048, N_LEVELS=4
// R1: MFMA flash attention. R5: branch-MLP ancestor dedup.
// R6/R7: 256^2 deep pipeline -> REGRESSED. R8: 128^2 + fused branch +
//     XCD/A-major remap: 785us. R9: BK64 + XOR swizzle: 751 (conflicts->0).
// R10: gemm64 for proj/w2: 722. R11: split-K: REGRESSED. R12: ~neutral.
// R13: gemm64 qkv(-6 WIN) + branch(+26 REGRESS). R14: combine-into-w2
//     staging fusion: REGRESSED HARD (lesson: staging fusion only for
//     near-zero-cost transforms).
// R15: best-of-each assembly (qkv->gemm64, branch->gemm128, proj/w2->
//     gemm64, separate combine + XCD-chunked remap): 702us. WIN.
// R16: safe micro-bundle (GEMMs at measured structural plateau):
//     (a) attn exp2-domain softmax: v_exp_f32 IS 2^x; folding log2e into
//         the score scale (0.125 -> 0.18033688) deletes ~60 v_mul/wave-tile
//         (__expf = v_mul+v_exp; exp2f = v_exp). Base-2 online softmax is
//         mathematically identical.
//     (b) ln_kernel float2/bf16x2 vectorization (G13, 2x load width).
//     (c) prep fusion: 4 dispatches -> 1 (3 fewer launch gaps on the
//         serial chain) + 4 elems/thread (f32x4 reads, 8B writes).
//     Attn LDS swizzle REJECTED by arithmetic: pad-72 reads are 2-way
//     aliasing (free, m136) and occupancy is VGPR-capped -> null.
// ---------------------------------------------------------------------------

typedef __attribute__((ext_vector_type(8))) __bf16 bf16x8;
typedef __attribute__((ext_vector_type(4))) __bf16 bf16x4;
typedef __attribute__((ext_vector_type(2))) __bf16 bf16x2;
typedef __attribute__((ext_vector_type(4))) float f32x4;
typedef __attribute__((ext_vector_type(2))) float f32x2;
typedef __attribute__((ext_vector_type(4))) unsigned int u32x4;

#define GF_RELU    1
#define GF_OUTBF16 2

static __device__ __forceinline__ bf16x8 bzero8() {
    u32x4 z = {0u, 0u, 0u, 0u};
    return __builtin_bit_cast(bf16x8, z);
}

// ---------------------------------------------------------------------------
// R16 fused prep kernel: all weight prep in ONE dispatch, 4 elems/thread.
//   j0 [0,768):      wqkvT  (K=512,  N=1536)  transpose+cvt
//   j1 [768,1024):   wprojT (K=512,  N=512)   transpose+cvt
//   j2 [1024,2048):  w2T    (K=2048, N=512)   transpose+cvt
//   j3 [2048,17408): wcat   pack (15 x 1M elems, strided copy+cvt)
// ---------------------------------------------------------------------------
__global__ __launch_bounds__(256) void prep_kernel(
    const float* __restrict__ w_qkv, const float* __restrict__ w_proj,
    const float* __restrict__ w2, const float* __restrict__ M,
    __hip_bfloat16* __restrict__ wqkvT, __hip_bfloat16* __restrict__ wprojT,
    __hip_bfloat16* __restrict__ w2T, __hip_bfloat16* __restrict__ wcat) {
    const int bid = blockIdx.x;
    if (bid < 2048) {
        // transpose jobs
        const float* in;
        __hip_bfloat16* out;
        int N, log2K, loc;
        if (bid < 768)       { in = w_qkv;  out = wqkvT;  N = 1536; log2K = 9;  loc = bid; }
        else if (bid < 1024) { in = w_proj; out = wprojT; N = 512;  log2K = 9;  loc = bid - 768; }
        else                 { in = w2;     out = w2T;    N = 512;  log2K = 11; loc = bid - 1024; }
        int idx4 = (loc * 256 + threadIdx.x) << 2;
        int n = idx4 >> log2K;
        int k = idx4 & ((1 << log2K) - 1);
        bf16x4 o;
        #pragma unroll
        for (int u = 0; u < 4; u++)
            o[u] = (__bf16)__float2bfloat16(in[(size_t)(k + u) * N + n]);
        *(bf16x4*)(out + idx4) = o;
    } else {
        // pack_wcat: 15 (s,d) pairs x 1024 blocks each
        int loc = bid - 2048;
        int p = loc >> 10;          // 0..14
        int blk = loc & 1023;
        int s, d;
        if (p < 5)       { s = 0; d = p; }
        else if (p < 9)  { s = 1; d = p - 4; }
        else if (p < 12) { s = 2; d = p - 7; }
        else if (p < 14) { s = 3; d = p - 9; }
        else             { s = 4; d = 4; }
        const int base_lut[5] = {0, 5, 9, 12, 14};
        size_t idx4 = ((size_t)blk * 256 + threadIdx.x) << 2;
        const size_t MB = 2048ull * 512;
        f32x4 v = *(const f32x4*)(M + ((size_t)d * 5 + s) * MB + idx4);
        bf16x4 o;
        #pragma unroll
        for (int u = 0; u < 4; u++) o[u] = (__bf16)__float2bfloat16(v[u]);
        *(bf16x4*)(wcat + (size_t)base_lut[s] * MB + (size_t)(d - s) * MB + idx4) = o;
    }
}

// ---------------------------------------------------------------------------
// LayerNorm over E=512, one block (256 threads) per token; float2 loads,
// bf16x2 stores (R16 vectorization).
// ---------------------------------------------------------------------------
__global__ __launch_bounds__(256) void ln_kernel(const float* __restrict__ x,
                                                 const float* __restrict__ g,
                                                 const float* __restrict__ b,
                                                 __hip_bfloat16* __restrict__ out) {
    int tok = blockIdx.x;
    const float* xr = x + (size_t)tok * 512;
    int t = threadIdx.x;
    f32x2 v = *(const f32x2*)(xr + 2 * t);
    float s = v[0] + v[1];
    float s2 = v[0] * v[0] + v[1] * v[1];
    #pragma unroll
    for (int o = 32; o > 0; o >>= 1) {
        s  += __shfl_down(s, o);
        s2 += __shfl_down(s2, o);
    }
    __shared__ float ps[4], ps2[4];
    int w = t >> 6, lane = t & 63;
    if (lane == 0) { ps[w] = s; ps2[w] = s2; }
    __syncthreads();
    if (t == 0) {
        float ts = 0.f, ts2 = 0.f;
        #pragma unroll
        for (int i = 0; i < 4; i++) { ts += ps[i]; ts2 += ps2[i]; }
        ps[0] = ts * (1.f / 512.f);
        ps2[0] = ts2 * (1.f / 512.f);
    }
    __syncthreads();
    float m = ps[0];
    float var = ps2[0] - m * m;
    float r = rsqrtf(var + 1e-5f);
    f32x2 gv = *(const f32x2*)(g + 2 * t);
    f32x2 bv = *(const f32x2*)(b + 2 * t);
    bf16x2 o;
    o[0] = (__bf16)__float2bfloat16((v[0] - m) * r * gv[0] + bv[0]);
    o[1] = (__bf16)__float2bfloat16((v[1] - m) * r * gv[1] + bv[1]);
    *(bf16x2*)(out + (size_t)tok * 512 + 2 * t) = o;
}

// ---------------------------------------------------------------------------
// MFMA flash attention. R16: exp2-domain online softmax (scale folded with
// log2e; v_exp_f32 is natively 2^x -> saves the v_mul per exp).
// ---------------------------------------------------------------------------
#define ATT_STR 72
#define SC2 0.18033688f   // 0.125 * log2(e)
__global__ __launch_bounds__(256) void attn_mfma_kernel(const __hip_bfloat16* __restrict__ qkv,
                                                        __hip_bfloat16* __restrict__ ctx) {
    __shared__ __bf16 kt_lds[64 * ATT_STR];
    __shared__ __bf16 vt_lds[64 * ATT_STR];
    __shared__ __bf16 pbuf[4 * 48 * ATT_STR];

    const int bh = blockIdx.x;
    const int half = blockIdx.y;
    const int b = bh >> 3, h = bh & 7;
    const int tid = threadIdx.x;
    const int w = tid >> 6, lane = tid & 63;
    const int q = lane >> 4, l16 = lane & 15;
    const int rowbase = half * 192 + w * 48;
    __bf16* pw = pbuf + w * 48 * ATT_STR;

    bf16x8 qf[3][2];
    #pragma unroll
    for (int mi = 0; mi < 3; mi++) {
        int row = rowbase + mi * 16 + l16;
        #pragma unroll
        for (int ks = 0; ks < 2; ks++) {
            if (row < 341)
                qf[mi][ks] = *(const bf16x8*)(qkv + (size_t)(b * 341 + row) * 1536 +
                                              h * 64 + ks * 32 + q * 8);
            else
                qf[mi][ks] = bzero8();
        }
    }

    f32x4 O[3][4];
    float mrun[3][4], lrun[3][4];
    #pragma unroll
    for (int mi = 0; mi < 3; mi++) {
        #pragma unroll
        for (int ni = 0; ni < 4; ni++) { f32x4 z = {0.f,0.f,0.f,0.f}; O[mi][ni] = z; }
        #pragma unroll
        for (int rr = 0; rr < 4; rr++) { mrun[mi][rr] = -1e30f; lrun[mi][rr] = 0.f; }
    }

    for (int kt6 = 0; kt6 < 6; kt6++) {
        const int kbase = kt6 * 64;
        __syncthreads();
        {
            int key = tid >> 2, kg = tid & 3;
            int gk = kbase + key;
            bf16x8 a0 = bzero8(), a1 = bzero8();
            if (gk < 341) {
                const __hip_bfloat16* src =
                    qkv + (size_t)(b * 341 + gk) * 1536 + 512 + h * 64 + kg * 16;
                a0 = *(const bf16x8*)src;
                a1 = *(const bf16x8*)(src + 8);
            }
            *(bf16x8*)(kt_lds + key * ATT_STR + kg * 16)     = a0;
            *(bf16x8*)(kt_lds + key * ATT_STR + kg * 16 + 8) = a1;
        }
        {
            int key = tid & 63, dg = tid >> 6;
            int gk = kbase + key;
            bf16x8 a0 = bzero8(), a1 = bzero8();
            if (gk < 341) {
                const __hip_bfloat16* src =
                    qkv + (size_t)(b * 341 + gk) * 1536 + 1024 + h * 64 + dg * 16;
                a0 = *(const bf16x8*)src;
                a1 = *(const bf16x8*)(src + 8);
            }
            #pragma unroll
            for (int j = 0; j < 8; j++) {
                vt_lds[(dg * 16 + j) * ATT_STR + key]     = a0[j];
                vt_lds[(dg * 16 + 8 + j) * ATT_STR + key] = a1[j];
            }
        }
        __syncthreads();

        f32x4 S[3][4];
        #pragma unroll
        for (int mi = 0; mi < 3; mi++)
            #pragma unroll
            for (int ni = 0; ni < 4; ni++) { f32x4 z = {0.f,0.f,0.f,0.f}; S[mi][ni] = z; }
        #pragma unroll
        for (int ks = 0; ks < 2; ks++) {
            bf16x8 bf_[4];
            #pragma unroll
            for (int ni = 0; ni < 4; ni++)
                bf_[ni] = *(const bf16x8*)(kt_lds + (ni * 16 + l16) * ATT_STR + ks * 32 + q * 8);
            #pragma unroll
            for (int mi = 0; mi < 3; mi++)
                #pragma unroll
                for (int ni = 0; ni < 4; ni++)
                    S[mi][ni] = __builtin_amdgcn_mfma_f32_16x16x32_bf16(qf[mi][ks], bf_[ni],
                                                                        S[mi][ni], 0, 0, 0);
        }

        float cmask[4];
        #pragma unroll
        for (int ni = 0; ni < 4; ni++)
            cmask[ni] = (kbase + ni * 16 + l16 < 341) ? 0.f : -1e30f;

        #pragma unroll
        for (int mi = 0; mi < 3; mi++) {
            #pragma unroll
            for (int rr = 0; rr < 4; rr++) {
                float rmax = -1e30f;
                #pragma unroll
                for (int ni = 0; ni < 4; ni++)
                    rmax = fmaxf(rmax, fmaf(S[mi][ni][rr], SC2, cmask[ni]));
                rmax = fmaxf(rmax, __shfl_xor(rmax, 1));
                rmax = fmaxf(rmax, __shfl_xor(rmax, 2));
                rmax = fmaxf(rmax, __shfl_xor(rmax, 4));
                rmax = fmaxf(rmax, __shfl_xor(rmax, 8));
                float mnew = fmaxf(mrun[mi][rr], rmax);
                float alpha = exp2f(mrun[mi][rr] - mnew);
                mrun[mi][rr] = mnew;
                float psum = 0.f;
                #pragma unroll
                for (int ni = 0; ni < 4; ni++) {
                    float p = exp2f(fmaf(S[mi][ni][rr], SC2, cmask[ni]) - mnew);
                    S[mi][ni][rr] = p;
                    psum += p;
                    O[mi][ni][rr] *= alpha;
                }
                psum += __shfl_xor(psum, 1);
                psum += __shfl_xor(psum, 2);
                psum += __shfl_xor(psum, 4);
                psum += __shfl_xor(psum, 8);
                lrun[mi][rr] = lrun[mi][rr] * alpha + psum;
            }
            #pragma unroll
            for (int ni = 0; ni < 4; ni++)
                #pragma unroll
                for (int rr = 0; rr < 4; rr++)
                    pw[(mi * 16 + q * 4 + rr) * ATT_STR + ni * 16 + l16] =
                        (__bf16)S[mi][ni][rr];
        }
        __syncthreads();

        #pragma unroll
        for (int ks = 0; ks < 2; ks++) {
            bf16x8 pf[3], vf[4];
            #pragma unroll
            for (int mi = 0; mi < 3; mi++)
                pf[mi] = *(const bf16x8*)(pw + (mi * 16 + l16) * ATT_STR + ks * 32 + q * 8);
            #pragma unroll
            for (int ni = 0; ni < 4; ni++)
                vf[ni] = *(const bf16x8*)(vt_lds + (ni * 16 + l16) * ATT_STR + ks * 32 + q * 8);
            #pragma unroll
            for (int mi = 0; mi < 3; mi++)
                #pragma unroll
                for (int ni = 0; ni < 4; ni++)
                    O[mi][ni] = __builtin_amdgcn_mfma_f32_16x16x32_bf16(pf[mi], vf[ni],
                                                                        O[mi][ni], 0, 0, 0);
        }
    }

    #pragma unroll
    for (int mi = 0; mi < 3; mi++) {
        #pragma unroll
        for (int rr = 0; rr < 4; rr++) {
            int row = rowbase + mi * 16 + q * 4 + rr;
            if (row >= 341) continue;
            float inv = 1.f / lrun[mi][rr];
            __hip_bfloat16* op = ctx + (size_t)(b * 341 + row) * 512 + h * 64;
            #pragma unroll
            for (int ni = 0; ni < 4; ni++)
                op[ni * 16 + l16] = __float2bfloat16(O[mi][ni][rr] * inv);
        }
    }
}

// bijective XCD-aware remap (m204): each XCD gets a contiguous chunk of the
// logical (A-major) tile order -> neighboring tiles sharing an A row-panel
// land on the same XCD's L2.
static __device__ __forceinline__ int xcd_remap(int bid, int nwg) {
    const int xcd = bid & 7, o = bid >> 3;
    const int qq = nwg >> 3, rr = nwg & 7;
    return (xcd < rr ? xcd * (qq + 1) : rr * (qq + 1) + (xcd - rr) * qq) + o;
}

// ---------------------------------------------------------------------------
// gemm128 body (128x128xBK64, register staging, both-sides XOR swizzle).
// Used by the fused branch GEMM only (deep grid; R13 proved 64x128 hurts it).
// ---------------------------------------------------------------------------
template <bool GATHER>
static __device__ __forceinline__ void gemm128_body(
    __hip_bfloat16* As, __hip_bfloat16* Bs,
    const __hip_bfloat16* __restrict__ A, const __hip_bfloat16* __restrict__ Bt,
    const float* __restrict__ bias, const float* __restrict__ resid,
    float* __restrict__ Cf, __hip_bfloat16* __restrict__ Cb,
    int Mrows, int N, int K, int flags, int depth, int bm0, int bn0) {
    const int tid = threadIdx.x;
    const int r = tid >> 1;            // staging row 0..127
    const int khalf = tid & 1;         // 0/1 -> 32-element (64B) half of row
    const int gr = bm0 + r;
    const int gn = bn0 + r;
    const int lane = tid & 63;
    const int w = tid >> 6;
    const int wm = (w >> 1) << 6;
    const int wn = (w & 1) << 6;
    const int q = lane >> 4;
    const int l16 = lane & 15;

    int wsl[4];
    #pragma unroll
    for (int j = 0; j < 4; j++)
        wsl[j] = ((((khalf << 2) | j) ^ (r & 7)) << 3);
    const int rs0 = ((q ^ (l16 & 7)) << 3);
    const int rs1 = (((4 + q) ^ (l16 & 7)) << 3);

    size_t abase;
    if (GATHER) {
        const int dsh = depth << 1;
        const int bmask = (1 << dsh) - 1;
        int b = gr >> dsh;
        int i = gr & bmask;
        int node = (0x55555555 & bmask) + i;   // offs[depth] + i
        abase = ((size_t)(b * 341 + node)) << 9;
    } else {
        abase = (size_t)gr * K;
    }

    f32x4 acc[4][4];
    #pragma unroll
    for (int i = 0; i < 4; i++)
        #pragma unroll
        for (int j = 0; j < 4; j++) {
            f32x4 z = {0.f, 0.f, 0.f, 0.f};
            acc[i][j] = z;
        }

    for (int k0 = 0; k0 < K; k0 += 64) {
        bf16x8 va[4], vb[4];
        if (gr < Mrows) {
            const bf16x8* p = (const bf16x8*)(A + abase + k0 + (khalf << 5));
            #pragma unroll
            for (int j = 0; j < 4; j++) va[j] = p[j];
        } else {
            #pragma unroll
            for (int j = 0; j < 4; j++) va[j] = bzero8();
        }
        {
            const bf16x8* p = (const bf16x8*)(Bt + (size_t)gn * K + k0 + (khalf << 5));
            #pragma unroll
            for (int j = 0; j < 4; j++) vb[j] = p[j];
        }
        __syncthreads();  // previous iteration's fragment reads complete
        #pragma unroll
        for (int j = 0; j < 4; j++) {
            *(bf16x8*)(As + r * 64 + wsl[j]) = va[j];
            *(bf16x8*)(Bs + r * 64 + wsl[j]) = vb[j];
        }
        __syncthreads();
        bf16x8 af[4][2], bfr[4][2];
        #pragma unroll
        for (int mi = 0; mi < 4; mi++) {
            const __hip_bfloat16* rp = As + (wm + mi * 16 + l16) * 64;
            af[mi][0] = *(const bf16x8*)(rp + rs0);
            af[mi][1] = *(const bf16x8*)(rp + rs1);
        }
        #pragma unroll
        for (int ni = 0; ni < 4; ni++) {
            const __hip_bfloat16* rp = Bs + (wn + ni * 16 + l16) * 64;
            bfr[ni][0] = *(const bf16x8*)(rp + rs0);
            bfr[ni][1] = *(const bf16x8*)(rp + rs1);
        }
        #pragma unroll
        for (int ks = 0; ks < 2; ks++)
            #pragma unroll
            for (int mi = 0; mi < 4; mi++)
                #pragma unroll
                for (int ni = 0; ni < 4; ni++)
                    acc[mi][ni] = __builtin_amdgcn_mfma_f32_16x16x32_bf16(
                        af[mi][ks], bfr[ni][ks], acc[mi][ni], 0, 0, 0);
    }

    #pragma unroll
    for (int mi = 0; mi < 4; mi++) {
        #pragma unroll
        for (int rr = 0; rr < 4; rr++) {
            int grow = bm0 + wm + mi * 16 + q * 4 + rr;
            if (grow >= Mrows) continue;
            size_t obase = (size_t)grow * N;
            #pragma unroll
            for (int ni = 0; ni < 4; ni++) {
                int col = bn0 + wn + ni * 16 + l16;
                float v = acc[mi][ni][rr];
                if (bias) v += bias[col];
                if (resid) v += resid[obase + col];
                if (flags & GF_RELU) v = fmaxf(v, 0.f);
                if (flags & GF_OUTBF16)
                    Cb[obase + col] = __float2bfloat16(v);
                else
                    Cf[obase + col] = v;
            }
        }
    }
}

// ---------------------------------------------------------------------------
// gemm64: 64(M)x128(N)xBK64 for qkv, proj, w2. 256 threads = 4 waves, each
// wave 64x32 (acc[4][2] = 32 AGPR; ~72 unified regs -> 6 blocks/CU with
// 24KB LDS). Register staging + both-sides XOR slot swizzle (R9/R10).
// ---------------------------------------------------------------------------
__global__ __launch_bounds__(256, 6) void gemm64(
    const __hip_bfloat16* __restrict__ A, const __hip_bfloat16* __restrict__ Bt,
    const float* __restrict__ bias, const float* __restrict__ resid,
    float* __restrict__ Cf, __hip_bfloat16* __restrict__ Cb,
    int Mrows, int N, int K, int flags, int gridN) {
    __shared__ __hip_bfloat16 As[64 * 64];
    __shared__ __hip_bfloat16 Bs[128 * 64];
    const int lin = xcd_remap(blockIdx.x, gridDim.x);
    const int bx = lin / gridN;           // A-major
    const int by = lin - bx * gridN;
    const int bm0 = bx << 6, bn0 = by << 7;

    const int tid = threadIdx.x;
    const int ra = tid >> 2, kq = tid & 3;      // A: 4 threads/row, 2 slots
    const int rb = tid >> 1, khalf = tid & 1;   // B: 2 threads/row, 4 slots
    const int lane = tid & 63;
    const int w = tid >> 6;
    const int wn = w << 5;                      // wave col offset 0/32/64/96
    const int q = lane >> 4;
    const int l16 = lane & 15;

    const int gra = bm0 + ra;
    const int gnb = bn0 + rb;

    int wslA[2];
    #pragma unroll
    for (int j = 0; j < 2; j++)
        wslA[j] = ((((kq << 1) | j) ^ (ra & 7)) << 3);
    int wslB[4];
    #pragma unroll
    for (int j = 0; j < 4; j++)
        wslB[j] = ((((khalf << 2) | j) ^ (rb & 7)) << 3);
    const int rs0 = ((q ^ (l16 & 7)) << 3);
    const int rs1 = (((4 + q) ^ (l16 & 7)) << 3);

    const size_t abase = (size_t)gra * K;

    f32x4 acc[4][2];
    #pragma unroll
    for (int i = 0; i < 4; i++)
        #pragma unroll
        for (int j = 0; j < 2; j++) {
            f32x4 z = {0.f, 0.f, 0.f, 0.f};
            acc[i][j] = z;
        }

    for (int k0 = 0; k0 < K; k0 += 64) {
        bf16x8 va[2], vb[4];
        if (gra < Mrows) {
            const bf16x8* p = (const bf16x8*)(A + abase + k0 + (kq << 4));
            #pragma unroll
            for (int j = 0; j < 2; j++) va[j] = p[j];
        } else {
            #pragma unroll
            for (int j = 0; j < 2; j++) va[j] = bzero8();
        }
        {
            const bf16x8* p = (const bf16x8*)(Bt + (size_t)gnb * K + k0 + (khalf << 5));
            #pragma unroll
            for (int j = 0; j < 4; j++) vb[j] = p[j];
        }
        __syncthreads();  // previous iteration's fragment reads complete
        #pragma unroll
        for (int j = 0; j < 2; j++)
            *(bf16x8*)(As + ra * 64 + wslA[j]) = va[j];
        #pragma unroll
        for (int j = 0; j < 4; j++)
            *(bf16x8*)(Bs + rb * 64 + wslB[j]) = vb[j];
        __syncthreads();
        bf16x8 af[4][2], bfr[2][2];
        #pragma unroll
        for (int mi = 0; mi < 4; mi++) {
            const __hip_bfloat16* rp = As + (mi * 16 + l16) * 64;
            af[mi][0] = *(const bf16x8*)(rp + rs0);
            af[mi][1] = *(const bf16x8*)(rp + rs1);
        }
        #pragma unroll
        for (int ni = 0; ni < 2; ni++) {
            const __hip_bfloat16* rp = Bs + (wn + ni * 16 + l16) * 64;
            bfr[ni][0] = *(const bf16x8*)(rp + rs0);
            bfr[ni][1] = *(const bf16x8*)(rp + rs1);
        }
        #pragma unroll
        for (int ks = 0; ks < 2; ks++)
            #pragma unroll
            for (int mi = 0; mi < 4; mi++)
                #pragma unroll
                for (int ni = 0; ni < 2; ni++)
                    acc[mi][ni] = __builtin_amdgcn_mfma_f32_16x16x32_bf16(
                        af[mi][ks], bfr[ni][ks], acc[mi][ni], 0, 0, 0);
    }

    #pragma unroll
    for (int mi = 0; mi < 4; mi++) {
        #pragma unroll
        for (int rr = 0; rr < 4; rr++) {
            int grow = bm0 + mi * 16 + q * 4 + rr;
            if (grow >= Mrows) continue;
            size_t obase = (size_t)grow * N;
            #pragma unroll
            for (int ni = 0; ni < 2; ni++) {
                int col = bn0 + wn + ni * 16 + l16;
                float v = acc[mi][ni][rr];
                if (bias) v += bias[col];
                if (resid) v += resid[obase + col];
                if (flags & GF_RELU) v = fmaxf(v, 0.f);
                if (flags & GF_OUTBF16)
                    Cb[obase + col] = __float2bfloat16(v);
                else
                    Cf[obase + col] = v;
            }
        }
    }
}

// ---------------------------------------------------------------------------
// Fused branch-MLP GEMM (R8-R12 proven): all 5 source-depth levels in ONE
// 3664-block dispatch at 128^2 tiles (s=0: 1x80, s=1: 2x64, s=2: 8x48,
// s=3: 32x32, s=4: 128x16). K=512 for all.
// ---------------------------------------------------------------------------
__global__ __launch_bounds__(256) void gemm_branch_fused(
    const __hip_bfloat16* __restrict__ xn, const __hip_bfloat16* __restrict__ wcat,
    __hip_bfloat16* __restrict__ Y) {
    __shared__ __hip_bfloat16 As[128 * 64];
    __shared__ __hip_bfloat16 Bs[128 * 64];
    const int lin = xcd_remap(blockIdx.x, gridDim.x);
    int s;
    if (lin < 80)        s = 0;
    else if (lin < 208)  s = 1;
    else if (lin < 592)  s = 2;
    else if (lin < 1616) s = 3;
    else                 s = 4;
    const int base_tab[5] = {0, 80, 208, 592, 1616};
    const int gn_tab[5]   = {80, 64, 48, 32, 16};
    const size_t yoff[5]  = {0, 655360, 2752512, 9043968, 25821184};
    const int wcat_off[5] = {0, 5, 9, 12, 14};
    const int loc = lin - base_tab[s];
    const int gn = gn_tab[s];
    const int bx = loc / gn;              // A-major within each s
    const int by = loc - bx * gn;
    const int Mrows = 64 << (s << 1);
    const int N = (5 - s) << 11;
    gemm128_body<true>(As, Bs, xn, wcat + (size_t)wcat_off[s] * (2048ull * 512),
                       nullptr, nullptr, nullptr, Y + yoff[s],
                       Mrows, N, 512, GF_OUTBF16, s, bx << 7, by << 7);
}

// ---------------------------------------------------------------------------
// Combine: h[b,node@d,:] = ReLU( sum_{s<=d} Y_s[...] + b1[node] ).
// R15: XCD-chunked remap (same-batch rows share ancestor Y segments).
// ---------------------------------------------------------------------------
__global__ __launch_bounds__(256) void combine_kernel(const __hip_bfloat16* __restrict__ Y,
                                                      const float* __restrict__ b1,
                                                      __hip_bfloat16* __restrict__ h) {
    const size_t yoff[5] = {0, 655360, 2752512, 9043968, 25821184};
    int row = xcd_remap(blockIdx.x, gridDim.x);
    int b = row / 341;
    int node = row - b * 341;
    int d = (node >= 85) ? 4 : (node >= 21) ? 3 : (node >= 5) ? 2 : (node >= 1) ? 1 : 0;
    int i = node - (0x55555555 & ((1 << (d << 1)) - 1));
    int j = threadIdx.x << 3;

    float acc[8];
    const float* bp = b1 + (size_t)node * 2048 + j;
    f32x4 b0 = *(const f32x4*)bp;
    f32x4 b4 = *(const f32x4*)(bp + 4);
    #pragma unroll
    for (int u = 0; u < 4; u++) { acc[u] = b0[u]; acc[u + 4] = b4[u]; }

    #pragma unroll
    for (int s = 0; s < 5; s++) {
        if (s <= d) {
            int a = i >> ((d - s) << 1);
            int width = (5 - s) << 11;
            const bf16x8 v = *(const bf16x8*)(Y + yoff[s] +
                (size_t)((b << (s << 1)) + a) * width + ((d - s) << 11) + j);
            #pragma unroll
            for (int u = 0; u < 8; u++) acc[u] += (float)v[u];
        }
    }
    bf16x8 o;
    #pragma unroll
    for (int u = 0; u < 8; u++) o[u] = (__bf16)fmaxf(acc[u], 0.f);
    *(bf16x8*)(h + (size_t)row * 2048 + j) = o;
}

// ---------------------------------------------------------------------------
extern "C" void kernel_launch(void* const* d_in, const int* in_sizes, int n_in,
                              void* d_out, int out_size, void* d_ws, size_t ws_size,
                              hipStream_t stream) {
    const float* x      = (const float*)d_in[0];
    const float* ln1_g  = (const float*)d_in[1];
    const float* ln1_b  = (const float*)d_in[2];
    const float* w_qkv  = (const float*)d_in[3];
    const float* b_qkv  = (const float*)d_in[4];
    const float* w_proj = (const float*)d_in[5];
    const float* b_proj = (const float*)d_in[6];
    const float* ln2_g  = (const float*)d_in[7];
    const float* ln2_b  = (const float*)d_in[8];
    const float* mlp_M  = (const float*)d_in[9];
    const float* mlp_b1 = (const float*)d_in[10];
    const float* w2     = (const float*)d_in[11];
    const float* b2     = (const float*)d_in[12];
    float* out = (float*)d_out;

    const int M = 64 * 341;  // 21824 rows

    char* ws = (char*)d_ws;
    size_t off = 0;
    auto alloc = [&](size_t bytes) -> char* {
        char* p = ws + off;
        off += (bytes + 255) & ~(size_t)255;
        return p;
    };
    __hip_bfloat16* xn     = (__hip_bfloat16*)alloc((size_t)M * 512 * 2);
    __hip_bfloat16* wqkvT  = (__hip_bfloat16*)alloc(1536ull * 512 * 2);
    __hip_bfloat16* wprojT = (__hip_bfloat16*)alloc(512ull * 512 * 2);
    __hip_bfloat16* w2T    = (__hip_bfloat16*)alloc(512ull * 2048 * 2);
    __hip_bfloat16* wcat   = (__hip_bfloat16*)alloc(15ull * 2048 * 512 * 2);
    __hip_bfloat16* hbuf   = (__hip_bfloat16*)alloc((size_t)M * 2048 * 2);
    // shared region: qkv+ctx (attention phase) overlaid by Y (branch phase)
    const size_t qkv_bytes = (size_t)M * 1536 * 2;            // 67,043,328
    const size_t y_bytes   = 59375616ull * 2;                 // 118,751,232
    char* shared = alloc(y_bytes);                            // >= qkv+ctx
    __hip_bfloat16* qkv = (__hip_bfloat16*)shared;
    __hip_bfloat16* ctx = (__hip_bfloat16*)(shared + qkv_bytes);
    __hip_bfloat16* Y   = (__hip_bfloat16*)shared;
    if (off > ws_size) return;  // workspace too small -> clean validation failure

    auto g64 = [&](const __hip_bfloat16* A, const __hip_bfloat16* Bt,
                   const float* bias, const float* resid, float* Cf,
                   __hip_bfloat16* Cb, int Mr, int N, int K, int flags) {
        int gm = (Mr + 63) >> 6, gn = N >> 7;
        gemm64<<<dim3(gm * gn), 256, 0, stream>>>(
            A, Bt, bias, resid, Cf, Cb, Mr, N, K, flags, gn);
    };

    // fused weight prep (one dispatch)
    prep_kernel<<<dim3(17408), 256, 0, stream>>>(w_qkv, w_proj, w2, mlp_M,
                                                 wqkvT, wprojT, w2T, wcat);

    // attention path (qkv on gemm64: R13-isolated win)
    ln_kernel<<<M, 256, 0, stream>>>(x, ln1_g, ln1_b, xn);
    g64(xn, wqkvT, b_qkv, nullptr, nullptr, qkv, M, 1536, 512, GF_OUTBF16);
    attn_mfma_kernel<<<dim3(512, 2), 256, 0, stream>>>(qkv, ctx);
    g64(ctx, wprojT, b_proj, x, out, nullptr, M, 512, 512, 0);

    // branch MLP path (dedup by source depth s) — single fused dispatch
    ln_kernel<<<M, 256, 0, stream>>>(out, ln2_g, ln2_b, xn);
    gemm_branch_fused<<<dim3(3664), 256, 0, stream>>>(xn, wcat, Y);
    combine_kernel<<<M, 256, 0, stream>>>(Y, mlp_b1, hbuf);
    g64(hbuf, w2T, b2, out, out, nullptr, M, 512, 2048, 0);
}